// Round 1
// baseline (19253.413 us; speedup 1.0000x reference)
//
#include <hip/hip_runtime.h>
#include <stdint.h>

#define EPSF 1e-4f

// ---------------- workspace layout (bytes) ----------------
// 0       : 16 floats of weight scales (slots 0..5 conv, 6..8 fc)
// 1024    : ternary conv weights (int8), then fc weights
// 2MB     : activation buffer A
// 64MB    : activation buffer B
#define OFF_SCALES  0
#define OFF_TC0     1024
#define OFF_TC1     2816        // 1024+1728 -> aligned
#define OFF_TC2     39680       // 2816+36864
#define OFF_TC3     113408      // +73728
#define OFF_TC4     260864      // +147456
#define OFF_TC5     555776      // +294912
#define OFF_TF0     1145600     // +589824
#define OFF_TF1     1276672     // +131072
#define OFF_TF2     1538816     // +262144
#define OFF_ACT_A   2097152
#define OFF_ACT_B   67108864

__global__ void zero_scales_k(float* s) {
    if (threadIdx.x < 16) s[threadIdx.x] = 0.f;
}

__global__ void absmax_k(const float* __restrict__ w, int n, float* slot) {
    __shared__ float red[256];
    float m = 0.f;
    for (int i = blockIdx.x * blockDim.x + threadIdx.x; i < n; i += gridDim.x * blockDim.x)
        m = fmaxf(m, fabsf(w[i]));
    red[threadIdx.x] = m;
    __syncthreads();
    for (int s2 = 128; s2 > 0; s2 >>= 1) {
        if ((int)threadIdx.x < s2) red[threadIdx.x] = fmaxf(red[threadIdx.x], red[threadIdx.x + s2]);
        __syncthreads();
    }
    if (threadIdx.x == 0) atomicMax((unsigned int*)slot, __float_as_uint(red[0]));
}

__global__ void ternarize_k(const float* __restrict__ w, int n, const float* __restrict__ slot,
                            int8_t* __restrict__ t) {
    int i = blockIdx.x * blockDim.x + threadIdx.x;
    if (i >= n) return;
    float s = slot[0];
    float q = rintf(w[i] / s);
    q = fminf(fmaxf(q, -1.f), 1.f);
    t[i] = (int8_t)q;
}

__global__ void quant_in_k(const float* __restrict__ x, int8_t* __restrict__ o, int n) {
    int i = blockIdx.x * blockDim.x + threadIdx.x;
    if (i >= n) return;
    float q = rintf(x[i] * 128.f);   // s = 2^-7 exactly
    q = fminf(fmaxf(q, -127.f), 127.f);
    o[i] = (int8_t)q;
}

// direct 3x3 VALID conv, int accumulate, fused BN + 2-bit quant
__global__ void conv_q_k(const int8_t* __restrict__ a, const int8_t* __restrict__ w,
                         const float* __restrict__ slot, const float* __restrict__ g,
                         const float* __restrict__ bb, const float* __restrict__ mm,
                         const float* __restrict__ vv, int8_t* __restrict__ out,
                         int B, int CI, int IH, int IW, int CO, int OH, int OW, float s_in) {
    int idx = blockIdx.x * blockDim.x + threadIdx.x;
    int total = B * CO * OH * OW;
    if (idx >= total) return;
    int ox = idx % OW;
    int t1 = idx / OW;
    int oy = t1 % OH;
    int t2 = t1 / OH;
    int co = t2 % CO;
    int b  = t2 / CO;

    const int8_t* wp = w + (size_t)co * CI * 9;
    int acc = 0;
    for (int ci = 0; ci < CI; ++ci) {
        const int8_t* ap = a + (((size_t)b * CI + ci) * IH + oy) * IW + ox;
        const int8_t* wr = wp + ci * 9;
#pragma unroll
        for (int ky = 0; ky < 3; ++ky) {
            const int8_t* ar = ap + ky * IW;
            acc += (int)ar[0] * (int)wr[ky * 3 + 0]
                 + (int)ar[1] * (int)wr[ky * 3 + 1]
                 + (int)ar[2] * (int)wr[ky * 3 + 2];
        }
    }
    float h = (float)acc * (s_in * slot[0]);
    float sc = g[co] / sqrtf(vv[co] + EPSF);
    h = (h - mm[co]) * sc + bb[co];
    float q = fminf(fmaxf(rintf(h), -1.f), 1.f);
    out[idx] = (int8_t)q;
}

__global__ void pool_k(const int8_t* __restrict__ a, int8_t* __restrict__ o,
                       int B, int C, int IH, int IW, int OH, int OW) {
    int idx = blockIdx.x * blockDim.x + threadIdx.x;
    int total = B * C * OH * OW;
    if (idx >= total) return;
    int ox = idx % OW;
    int t1 = idx / OW;
    int oy = t1 % OH;
    int t2 = t1 / OH;
    int c  = t2 % C;
    int b  = t2 / C;
    const int8_t* p = a + (((size_t)b * C + c) * IH + 2 * oy) * IW + 2 * ox;
    int m0 = max((int)p[0], (int)p[1]);
    int m1 = max((int)p[IW], (int)p[IW + 1]);
    o[idx] = (int8_t)max(m0, m1);
}

__global__ void fc_q_k(const int8_t* __restrict__ a, const int8_t* __restrict__ t,
                       const float* __restrict__ slot, const float* __restrict__ g,
                       const float* __restrict__ bb, const float* __restrict__ mm,
                       const float* __restrict__ vv, int8_t* __restrict__ out,
                       int B, int I, int O) {
    int idx = blockIdx.x * blockDim.x + threadIdx.x;
    int total = B * O;
    if (idx >= total) return;
    int o = idx % O;
    int b = idx / O;
    const int8_t* ar = a + (size_t)b * I;
    const int8_t* tr = t + (size_t)o * I;
    int acc = 0;
    for (int i = 0; i < I; i += 4) {
        acc += (int)ar[i]     * (int)tr[i]
             + (int)ar[i + 1] * (int)tr[i + 1]
             + (int)ar[i + 2] * (int)tr[i + 2]
             + (int)ar[i + 3] * (int)tr[i + 3];
    }
    float h = (float)acc * slot[0];
    float sc = g[o] / sqrtf(vv[o] + EPSF);
    h = (h - mm[o]) * sc + bb[o];
    out[idx] = (int8_t)fminf(fmaxf(rintf(h), -1.f), 1.f);
}

__global__ void fc_out_k(const int8_t* __restrict__ a, const int8_t* __restrict__ t,
                         const float* __restrict__ slot,
                         const float* __restrict__ tw, const float* __restrict__ tb,
                         const float* __restrict__ tm, const float* __restrict__ tv,
                         float* __restrict__ out, int B, int I, int O) {
    int idx = blockIdx.x * blockDim.x + threadIdx.x;
    int total = B * O;
    if (idx >= total) return;
    int o = idx % O;
    int b = idx / O;
    const int8_t* ar = a + (size_t)b * I;
    const int8_t* tr = t + (size_t)o * I;
    int acc = 0;
    for (int i = 0; i < I; i += 4) {
        acc += (int)ar[i]     * (int)tr[i]
             + (int)ar[i + 1] * (int)tr[i + 1]
             + (int)ar[i + 2] * (int)tr[i + 2]
             + (int)ar[i + 3] * (int)tr[i + 3];
    }
    float h = (float)acc * slot[0];
    h = (h - tm[0]) / sqrtf(tv[0] + EPSF) * tw[0] + tb[0];
    out[idx] = h;
}

static inline unsigned cdiv(long long a, int b) { return (unsigned)((a + b - 1) / b); }

extern "C" void kernel_launch(void* const* d_in, const int* in_sizes, int n_in,
                              void* d_out, int out_size, void* d_ws, size_t ws_size,
                              hipStream_t stream) {
    const float* x  = (const float*)d_in[0];
    // dict order: x, then per conv layer (cw, g, b, m, v), then fw0..2, fbn0, fbn1, tn
    const float* cw[6];  const float* bng[6]; const float* bnb[6];
    const float* bnm[6]; const float* bnv[6];
    for (int l = 0; l < 6; ++l) {
        cw[l]  = (const float*)d_in[1 + 5 * l + 0];
        bng[l] = (const float*)d_in[1 + 5 * l + 1];
        bnb[l] = (const float*)d_in[1 + 5 * l + 2];
        bnm[l] = (const float*)d_in[1 + 5 * l + 3];
        bnv[l] = (const float*)d_in[1 + 5 * l + 4];
    }
    const float* fw0 = (const float*)d_in[31];
    const float* fw1 = (const float*)d_in[32];
    const float* fw2 = (const float*)d_in[33];
    const float* fbn0[4] = { (const float*)d_in[34], (const float*)d_in[35],
                             (const float*)d_in[36], (const float*)d_in[37] };
    const float* fbn1[4] = { (const float*)d_in[38], (const float*)d_in[39],
                             (const float*)d_in[40], (const float*)d_in[41] };
    const float* tn_w = (const float*)d_in[42];
    const float* tn_b = (const float*)d_in[43];
    const float* tn_m = (const float*)d_in[44];
    const float* tn_v = (const float*)d_in[45];

    char* ws = (char*)d_ws;
    float* scales = (float*)(ws + OFF_SCALES);
    int8_t* tc[6] = { (int8_t*)(ws + OFF_TC0), (int8_t*)(ws + OFF_TC1), (int8_t*)(ws + OFF_TC2),
                      (int8_t*)(ws + OFF_TC3), (int8_t*)(ws + OFF_TC4), (int8_t*)(ws + OFF_TC5) };
    int8_t* tf[3] = { (int8_t*)(ws + OFF_TF0), (int8_t*)(ws + OFF_TF1), (int8_t*)(ws + OFF_TF2) };
    int8_t* actA = (int8_t*)(ws + OFF_ACT_A);
    int8_t* actB = (int8_t*)(ws + OFF_ACT_B);

    const int conv_wn[6] = { 64*3*9, 64*64*9, 128*64*9, 128*128*9, 256*128*9, 256*256*9 };
    const int fc_wn[3]   = { 512*256, 512*512, 10*512 };

    hipLaunchKernelGGL(zero_scales_k, dim3(1), dim3(16), 0, stream, scales);

    for (int l = 0; l < 6; ++l) {
        unsigned gb = cdiv(conv_wn[l], 256); if (gb > 1024) gb = 1024;
        hipLaunchKernelGGL(absmax_k, dim3(gb), dim3(256), 0, stream, cw[l], conv_wn[l], scales + l);
    }
    const float* fws[3] = { fw0, fw1, fw2 };
    for (int l = 0; l < 3; ++l) {
        unsigned gb = cdiv(fc_wn[l], 256); if (gb > 1024) gb = 1024;
        hipLaunchKernelGGL(absmax_k, dim3(gb), dim3(256), 0, stream, fws[l], fc_wn[l], scales + 6 + l);
    }
    for (int l = 0; l < 6; ++l)
        hipLaunchKernelGGL(ternarize_k, dim3(cdiv(conv_wn[l], 256)), dim3(256), 0, stream,
                           cw[l], conv_wn[l], scales + l, tc[l]);
    for (int l = 0; l < 3; ++l)
        hipLaunchKernelGGL(ternarize_k, dim3(cdiv(fc_wn[l], 256)), dim3(256), 0, stream,
                           fws[l], fc_wn[l], scales + 6 + l, tf[l]);

    const int B = 1024;
    // input quant: [1024,3,32,32]
    {
        int n = B * 3 * 32 * 32;
        hipLaunchKernelGGL(quant_in_k, dim3(cdiv(n, 256)), dim3(256), 0, stream, x, actA, n);
    }
    // conv0: 3->64, 32->30
    hipLaunchKernelGGL(conv_q_k, dim3(cdiv((long long)B*64*30*30, 256)), dim3(256), 0, stream,
                       actA, tc[0], scales + 0, bng[0], bnb[0], bnm[0], bnv[0], actB,
                       B, 3, 32, 32, 64, 30, 30, 0.0078125f);
    // conv1: 64->64, 30->28
    hipLaunchKernelGGL(conv_q_k, dim3(cdiv((long long)B*64*28*28, 256)), dim3(256), 0, stream,
                       actB, tc[1], scales + 1, bng[1], bnb[1], bnm[1], bnv[1], actA,
                       B, 64, 30, 30, 64, 28, 28, 1.0f);
    // pool: 28->14
    hipLaunchKernelGGL(pool_k, dim3(cdiv((long long)B*64*14*14, 256)), dim3(256), 0, stream,
                       actA, actB, B, 64, 28, 28, 14, 14);
    // conv2: 64->128, 14->12
    hipLaunchKernelGGL(conv_q_k, dim3(cdiv((long long)B*128*12*12, 256)), dim3(256), 0, stream,
                       actB, tc[2], scales + 2, bng[2], bnb[2], bnm[2], bnv[2], actA,
                       B, 64, 14, 14, 128, 12, 12, 1.0f);
    // conv3: 128->128, 12->10
    hipLaunchKernelGGL(conv_q_k, dim3(cdiv((long long)B*128*10*10, 256)), dim3(256), 0, stream,
                       actA, tc[3], scales + 3, bng[3], bnb[3], bnm[3], bnv[3], actB,
                       B, 128, 12, 12, 128, 10, 10, 1.0f);
    // pool: 10->5
    hipLaunchKernelGGL(pool_k, dim3(cdiv((long long)B*128*5*5, 256)), dim3(256), 0, stream,
                       actB, actA, B, 128, 10, 10, 5, 5);
    // conv4: 128->256, 5->3
    hipLaunchKernelGGL(conv_q_k, dim3(cdiv((long long)B*256*3*3, 256)), dim3(256), 0, stream,
                       actA, tc[4], scales + 4, bng[4], bnb[4], bnm[4], bnv[4], actB,
                       B, 128, 5, 5, 256, 3, 3, 1.0f);
    // conv5: 256->256, 3->1
    hipLaunchKernelGGL(conv_q_k, dim3(cdiv((long long)B*256*1*1, 256)), dim3(256), 0, stream,
                       actB, tc[5], scales + 5, bng[5], bnb[5], bnm[5], bnv[5], actA,
                       B, 256, 3, 3, 256, 1, 1, 1.0f);
    // fc0: 256->512
    hipLaunchKernelGGL(fc_q_k, dim3(cdiv((long long)B*512, 256)), dim3(256), 0, stream,
                       actA, tf[0], scales + 6, fbn0[0], fbn0[1], fbn0[2], fbn0[3], actB,
                       B, 256, 512);
    // fc1: 512->512
    hipLaunchKernelGGL(fc_q_k, dim3(cdiv((long long)B*512, 256)), dim3(256), 0, stream,
                       actB, tf[1], scales + 7, fbn1[0], fbn1[1], fbn1[2], fbn1[3], actA,
                       B, 512, 512);
    // fc2 + tensor norm: 512->10, float out
    hipLaunchKernelGGL(fc_out_k, dim3(cdiv((long long)B*10, 256)), dim3(256), 0, stream,
                       actA, tf[2], scales + 8, tn_w, tn_b, tn_m, tn_v,
                       (float*)d_out, B, 512, 10);
}

// Round 2
// 7430.276 us; speedup vs baseline: 2.5912x; 2.5912x over previous
//
#include <hip/hip_runtime.h>
#include <stdint.h>

#define EPSF 1e-4f

// ---------------- workspace layout (bytes) ----------------
#define OFF_SCALES  0           // 16 floats: slots 0..5 conv, 6..8 fc
#define OFF_FOLD    1024        // folded BN params (A then B per layer), floats
#define OFF_W       32768       // ternary weights
// ternary weight offsets (cumulative from OFF_W)
#define OFF_TC0     (OFF_W + 0)          // 64*9*4    = 2304
#define OFF_TC1     (OFF_W + 2304)       // 64*9*64   = 36864
#define OFF_TC2     (OFF_W + 39168)      // 128*9*64  = 73728
#define OFF_TC3     (OFF_W + 112896)     // 128*9*128 = 147456
#define OFF_TC4     (OFF_W + 260352)     // 256*9*128 = 294912
#define OFF_TC5     (OFF_W + 555264)     // 256*9*256 = 589824
#define OFF_TF0     (OFF_W + 1145088)    // 512*256   = 131072
#define OFF_TF1     (OFF_W + 1276160)    // 512*512   = 262144
#define OFF_TF2     (OFF_W + 1538304)    // 10*512    = 5120
#define OFF_ACT_A   2097152
#define OFF_ACT_B   60817408

// fold-param float offsets (within fold buffer)
// conv: l0:0(64) l1:128(64) l2:256(128) l3:512(128) l4:768(256) l5:1280(256)
// fc:   f0:1792(512) f1:2816(512)
static const int FOLD_OFF[8] = {0, 128, 256, 512, 768, 1280, 1792, 2816};

__device__ __forceinline__ int dot4(int a, int b, int c) {
#if __has_builtin(__builtin_amdgcn_sdot4)
    return __builtin_amdgcn_sdot4(a, b, c, false);
#else
    c += (int)(int8_t)(a) * (int)(int8_t)(b);
    c += (int)(int8_t)(a >> 8)  * (int)(int8_t)(b >> 8);
    c += (int)(int8_t)(a >> 16) * (int)(int8_t)(b >> 16);
    c += (int)(int8_t)(a >> 24) * (int)(int8_t)(b >> 24);
    return c;
#endif
}

__global__ void zero_scales_k(float* s) {
    if (threadIdx.x < 16) s[threadIdx.x] = 0.f;
}

__global__ void absmax_k(const float* __restrict__ w, int n, float* slot) {
    __shared__ float red[256];
    float m = 0.f;
    for (int i = blockIdx.x * blockDim.x + threadIdx.x; i < n; i += gridDim.x * blockDim.x)
        m = fmaxf(m, fabsf(w[i]));
    red[threadIdx.x] = m;
    __syncthreads();
    for (int s2 = 128; s2 > 0; s2 >>= 1) {
        if ((int)threadIdx.x < s2) red[threadIdx.x] = fmaxf(red[threadIdx.x], red[threadIdx.x + s2]);
        __syncthreads();
    }
    if (threadIdx.x == 0) atomicMax((unsigned int*)slot, __float_as_uint(red[0]));
}

// conv weight ternarize + transpose OIHW -> [co][ky][kx][ci_pad]
__global__ void tern_conv_k(const float* __restrict__ w, const float* __restrict__ slot,
                            int8_t* __restrict__ t, int CO, int CI, int CIp) {
    int idx = blockIdx.x * blockDim.x + threadIdx.x;
    int n = CO * 9 * CIp;
    if (idx >= n) return;
    int ci = idx % CIp;
    int t1 = idx / CIp;
    int kxy = t1 % 9;
    int co = t1 / 9;
    float val = 0.f;
    if (ci < CI) val = w[((size_t)co * CI + ci) * 9 + kxy];
    float q = fminf(fmaxf(rintf(val / slot[0]), -1.f), 1.f);
    t[idx] = (int8_t)q;
}

// fc weight ternarize (layout preserved [o][i])
__global__ void tern_fc_k(const float* __restrict__ w, int n, const float* __restrict__ slot,
                          int8_t* __restrict__ t) {
    int i = blockIdx.x * blockDim.x + threadIdx.x;
    if (i >= n) return;
    float q = fminf(fmaxf(rintf(w[i] / slot[0]), -1.f), 1.f);
    t[i] = (int8_t)q;
}

// fold BN: A = s_in*slot*g/sqrt(v+eps); B = b - m*g/sqrt(v+eps)
__global__ void bnfold_k(const float* __restrict__ slot, const float* __restrict__ g,
                         const float* __restrict__ b, const float* __restrict__ m,
                         const float* __restrict__ v, float s_in, int n,
                         float* __restrict__ fold) {
    int i = blockIdx.x * blockDim.x + threadIdx.x;
    if (i >= n) return;
    float sc = g[i] / sqrtf(v[i] + EPSF);
    fold[i] = s_in * slot[0] * sc;
    fold[n + i] = b[i] - m[i] * sc;
}

// input quant: NCHW float -> NHWC4 int8 (channel 3 = 0 pad)
__global__ void quant_in_k(const float* __restrict__ x, int* __restrict__ o, int B) {
    int idx = blockIdx.x * blockDim.x + threadIdx.x;
    int n = B * 1024;
    if (idx >= n) return;
    int p = idx & 1023;
    int b = idx >> 10;
    unsigned pk = 0;
#pragma unroll
    for (int c = 0; c < 3; ++c) {
        float q = rintf(x[((size_t)b * 3 + c) * 1024 + p] * 128.f);
        q = fminf(fmaxf(q, -127.f), 127.f);
        pk |= ((unsigned)((int)q & 0xff)) << (8 * c);
    }
    o[idx] = (int)pk;
}

// NHWC direct 3x3 conv, dot4, 8 co x 2 ox per thread, fused BN+quant
__global__ void conv_q_k(const int8_t* __restrict__ act, const int8_t* __restrict__ wt,
                         const float* __restrict__ fold, int8_t* __restrict__ out,
                         int B, int CI, int IH, int IW, int CO, int OH, int OW) {
    int co0 = blockIdx.y * 8;
    int npx = (OW + 1) >> 1;
    int sp = blockIdx.x * blockDim.x + threadIdx.x;
    int total = B * OH * npx;
    if (sp >= total) return;
    int oxp = sp % npx;
    int t1 = sp / npx;
    int oy = t1 % OH;
    int b = t1 / OH;
    int ox = oxp * 2;

    const int8_t* abase = act + (((size_t)b * IH + oy) * IW + ox) * CI;
    const int8_t* wbase = wt + (size_t)co0 * 9 * CI;

    int acc0[8] = {0,0,0,0,0,0,0,0};
    int acc1[8] = {0,0,0,0,0,0,0,0};

#pragma unroll
    for (int ky = 0; ky < 3; ++ky) {
#pragma unroll
        for (int kx = 0; kx < 3; ++kx) {
            const int8_t* ap = abase + ((size_t)ky * IW + kx) * CI;
            const int8_t* wp = wbase + (ky * 3 + kx) * CI;
            for (int ci = 0; ci < CI; ci += 4) {
                int a0 = *(const int*)(ap + ci);
                int a1 = *(const int*)(ap + CI + ci);
#pragma unroll
                for (int j = 0; j < 8; ++j) {
                    int w = *(const int*)(wp + (size_t)j * 9 * CI + ci);
                    acc0[j] = dot4(a0, w, acc0[j]);
                    acc1[j] = dot4(a1, w, acc1[j]);
                }
            }
        }
    }

    float Af[8], Bf[8];
#pragma unroll
    for (int j = 0; j < 8; ++j) {
        Af[j] = fold[co0 + j];
        Bf[j] = fold[CO + co0 + j];
    }
    unsigned p0 = 0, p1 = 0, q0 = 0, q1 = 0;
#pragma unroll
    for (int j = 0; j < 4; ++j) {
        int v0 = (int)fminf(fmaxf(rintf((float)acc0[j] * Af[j] + Bf[j]), -1.f), 1.f);
        int v1 = (int)fminf(fmaxf(rintf((float)acc0[j + 4] * Af[j + 4] + Bf[j + 4]), -1.f), 1.f);
        p0 |= ((unsigned)(v0 & 0xff)) << (8 * j);
        p1 |= ((unsigned)(v1 & 0xff)) << (8 * j);
    }
#pragma unroll
    for (int j = 0; j < 4; ++j) {
        int v0 = (int)fminf(fmaxf(rintf((float)acc1[j] * Af[j] + Bf[j]), -1.f), 1.f);
        int v1 = (int)fminf(fmaxf(rintf((float)acc1[j + 4] * Af[j + 4] + Bf[j + 4]), -1.f), 1.f);
        q0 |= ((unsigned)(v0 & 0xff)) << (8 * j);
        q1 |= ((unsigned)(v1 & 0xff)) << (8 * j);
    }
    size_t op = (((size_t)b * OH + oy) * OW + ox) * CO + co0;
    *(int*)(out + op) = (int)p0;
    *(int*)(out + op + 4) = (int)p1;
    if (ox + 1 < OW) {
        *(int*)(out + op + CO) = (int)q0;
        *(int*)(out + op + CO + 4) = (int)q1;
    }
}

// NHWC 2x2 maxpool, dword (4 channels) per thread
__global__ void pool_k(const int8_t* __restrict__ a, int8_t* __restrict__ o,
                       int B, int C, int IH, int IW, int OH, int OW) {
    int idx = blockIdx.x * blockDim.x + threadIdx.x;
    int c4n = C >> 2;
    int total = B * OH * OW * c4n;
    if (idx >= total) return;
    int c4 = idx % c4n;
    int t1 = idx / c4n;
    int ox = t1 % OW;
    int t2 = t1 / OW;
    int oy = t2 % OH;
    int b = t2 / OH;
    const int8_t* p = a + (((size_t)b * IH + 2 * oy) * IW + 2 * ox) * C + 4 * c4;
    int w0 = *(const int*)p;
    int w1 = *(const int*)(p + C);
    int w2 = *(const int*)(p + (size_t)IW * C);
    int w3 = *(const int*)(p + (size_t)IW * C + C);
    unsigned r = 0;
#pragma unroll
    for (int k = 0; k < 4; ++k) {
        int x0 = (int)(int8_t)(w0 >> (8 * k));
        int x1 = (int)(int8_t)(w1 >> (8 * k));
        int x2 = (int)(int8_t)(w2 >> (8 * k));
        int x3 = (int)(int8_t)(w3 >> (8 * k));
        int mx = max(max(x0, x1), max(x2, x3));
        r |= ((unsigned)(mx & 0xff)) << (8 * k);
    }
    *(int*)(o + (((size_t)b * OH + oy) * OW + ox) * C + 4 * c4) = (int)r;
}

// FC + BN + 2-bit quant, dot4
__global__ void fc_q_k(const int8_t* __restrict__ a, const int8_t* __restrict__ t,
                       const float* __restrict__ fold, int8_t* __restrict__ out,
                       int B, int I, int O) {
    int idx = blockIdx.x * blockDim.x + threadIdx.x;
    if (idx >= B * O) return;
    int o = idx % O;
    int b = idx / O;
    const int* ar = (const int*)(a + (size_t)b * I);
    const int* tr = (const int*)(t + (size_t)o * I);
    int acc = 0;
    for (int i = 0; i < (I >> 2); ++i) acc = dot4(ar[i], tr[i], acc);
    float h = (float)acc * fold[o] + fold[O + o];
    out[idx] = (int8_t)fminf(fmaxf(rintf(h), -1.f), 1.f);
}

// final FC + tensor norm -> float out
__global__ void fc_out_k(const int8_t* __restrict__ a, const int8_t* __restrict__ t,
                         const float* __restrict__ slot,
                         const float* __restrict__ tw, const float* __restrict__ tb,
                         const float* __restrict__ tm, const float* __restrict__ tv,
                         float* __restrict__ out, int B, int I, int O) {
    int idx = blockIdx.x * blockDim.x + threadIdx.x;
    if (idx >= B * O) return;
    int o = idx % O;
    int b = idx / O;
    const int* ar = (const int*)(a + (size_t)b * I);
    const int* tr = (const int*)(t + (size_t)o * I);
    int acc = 0;
    for (int i = 0; i < (I >> 2); ++i) acc = dot4(ar[i], tr[i], acc);
    float sc = tw[0] / sqrtf(tv[0] + EPSF);
    out[idx] = ((float)acc * slot[0] - tm[0]) * sc + tb[0];
}

static inline unsigned cdiv(long long a, int b) { return (unsigned)((a + b - 1) / b); }

extern "C" void kernel_launch(void* const* d_in, const int* in_sizes, int n_in,
                              void* d_out, int out_size, void* d_ws, size_t ws_size,
                              hipStream_t stream) {
    const float* x = (const float*)d_in[0];
    const float* cw[6]; const float* bng[6]; const float* bnb[6];
    const float* bnm[6]; const float* bnv[6];
    for (int l = 0; l < 6; ++l) {
        cw[l]  = (const float*)d_in[1 + 5 * l + 0];
        bng[l] = (const float*)d_in[1 + 5 * l + 1];
        bnb[l] = (const float*)d_in[1 + 5 * l + 2];
        bnm[l] = (const float*)d_in[1 + 5 * l + 3];
        bnv[l] = (const float*)d_in[1 + 5 * l + 4];
    }
    const float* fws[3] = { (const float*)d_in[31], (const float*)d_in[32], (const float*)d_in[33] };
    const float* fbn[2][4] = {
        { (const float*)d_in[34], (const float*)d_in[35], (const float*)d_in[36], (const float*)d_in[37] },
        { (const float*)d_in[38], (const float*)d_in[39], (const float*)d_in[40], (const float*)d_in[41] } };
    const float* tn_w = (const float*)d_in[42];
    const float* tn_b = (const float*)d_in[43];
    const float* tn_m = (const float*)d_in[44];
    const float* tn_v = (const float*)d_in[45];

    char* ws = (char*)d_ws;
    float* scales = (float*)(ws + OFF_SCALES);
    float* fold = (float*)(ws + OFF_FOLD);
    int8_t* tc[6] = { (int8_t*)(ws + OFF_TC0), (int8_t*)(ws + OFF_TC1), (int8_t*)(ws + OFF_TC2),
                      (int8_t*)(ws + OFF_TC3), (int8_t*)(ws + OFF_TC4), (int8_t*)(ws + OFF_TC5) };
    int8_t* tf[3] = { (int8_t*)(ws + OFF_TF0), (int8_t*)(ws + OFF_TF1), (int8_t*)(ws + OFF_TF2) };
    int8_t* actA = (int8_t*)(ws + OFF_ACT_A);
    int8_t* actB = (int8_t*)(ws + OFF_ACT_B);

    const int B = in_sizes[0] / 3072;
    const int conv_wn[6] = { 64*3*9, 64*64*9, 128*64*9, 128*128*9, 256*128*9, 256*256*9 };
    const int conv_CI[6]  = { 3, 64, 64, 128, 128, 256 };
    const int conv_CIp[6] = { 4, 64, 64, 128, 128, 256 };
    const int conv_CO[6]  = { 64, 64, 128, 128, 256, 256 };
    const int fc_wn[3] = { 512*256, 512*512, 10*512 };

    hipLaunchKernelGGL(zero_scales_k, dim3(1), dim3(16), 0, stream, scales);
    for (int l = 0; l < 6; ++l) {
        unsigned gb = cdiv(conv_wn[l], 256); if (gb > 1024) gb = 1024;
        hipLaunchKernelGGL(absmax_k, dim3(gb), dim3(256), 0, stream, cw[l], conv_wn[l], scales + l);
    }
    for (int l = 0; l < 3; ++l) {
        unsigned gb = cdiv(fc_wn[l], 256); if (gb > 1024) gb = 1024;
        hipLaunchKernelGGL(absmax_k, dim3(gb), dim3(256), 0, stream, fws[l], fc_wn[l], scales + 6 + l);
    }
    for (int l = 0; l < 6; ++l) {
        int n = conv_CO[l] * 9 * conv_CIp[l];
        hipLaunchKernelGGL(tern_conv_k, dim3(cdiv(n, 256)), dim3(256), 0, stream,
                           cw[l], scales + l, tc[l], conv_CO[l], conv_CI[l], conv_CIp[l]);
    }
    for (int l = 0; l < 3; ++l)
        hipLaunchKernelGGL(tern_fc_k, dim3(cdiv(fc_wn[l], 256)), dim3(256), 0, stream,
                           fws[l], fc_wn[l], scales + 6 + l, tf[l]);
    // BN folds: conv layers (s_in = 2^-7 for l0, else 1), fc layers
    for (int l = 0; l < 6; ++l)
        hipLaunchKernelGGL(bnfold_k, dim3(1), dim3(256), 0, stream,
                           scales + l, bng[l], bnb[l], bnm[l], bnv[l],
                           l == 0 ? 0.0078125f : 1.0f, conv_CO[l], fold + FOLD_OFF[l]);
    for (int l = 0; l < 2; ++l)
        hipLaunchKernelGGL(bnfold_k, dim3(2), dim3(256), 0, stream,
                           scales + 6 + l, fbn[l][0], fbn[l][1], fbn[l][2], fbn[l][3],
                           1.0f, 512, fold + FOLD_OFF[6 + l]);

    hipLaunchKernelGGL(quant_in_k, dim3(cdiv((long long)B * 1024, 256)), dim3(256), 0, stream,
                       x, (int*)actA, B);

    // conv0: 4->64, 32->30
    hipLaunchKernelGGL(conv_q_k, dim3(cdiv((long long)B * 30 * 15, 256), 8), dim3(256), 0, stream,
                       actA, tc[0], fold + FOLD_OFF[0], actB, B, 4, 32, 32, 64, 30, 30);
    // conv1: 64->64, 30->28
    hipLaunchKernelGGL(conv_q_k, dim3(cdiv((long long)B * 28 * 14, 256), 8), dim3(256), 0, stream,
                       actB, tc[1], fold + FOLD_OFF[1], actA, B, 64, 30, 30, 64, 28, 28);
    // pool 28->14
    hipLaunchKernelGGL(pool_k, dim3(cdiv((long long)B * 14 * 14 * 16, 256)), dim3(256), 0, stream,
                       actA, actB, B, 64, 28, 28, 14, 14);
    // conv2: 64->128, 14->12
    hipLaunchKernelGGL(conv_q_k, dim3(cdiv((long long)B * 12 * 6, 256), 16), dim3(256), 0, stream,
                       actB, tc[2], fold + FOLD_OFF[2], actA, B, 64, 14, 14, 128, 12, 12);
    // conv3: 128->128, 12->10
    hipLaunchKernelGGL(conv_q_k, dim3(cdiv((long long)B * 10 * 5, 256), 16), dim3(256), 0, stream,
                       actA, tc[3], fold + FOLD_OFF[3], actB, B, 128, 12, 12, 128, 10, 10);
    // pool 10->5
    hipLaunchKernelGGL(pool_k, dim3(cdiv((long long)B * 5 * 5 * 32, 256)), dim3(256), 0, stream,
                       actB, actA, B, 128, 10, 10, 5, 5);
    // conv4: 128->256, 5->3
    hipLaunchKernelGGL(conv_q_k, dim3(cdiv((long long)B * 3 * 2, 256), 32), dim3(256), 0, stream,
                       actA, tc[4], fold + FOLD_OFF[4], actB, B, 128, 5, 5, 256, 3, 3);
    // conv5: 256->256, 3->1
    hipLaunchKernelGGL(conv_q_k, dim3(cdiv((long long)B * 1 * 1, 256), 32), dim3(256), 0, stream,
                       actB, tc[5], fold + FOLD_OFF[5], actA, B, 256, 3, 3, 256, 1, 1);
    // fc0: 256->512
    hipLaunchKernelGGL(fc_q_k, dim3(cdiv((long long)B * 512, 256)), dim3(256), 0, stream,
                       actA, tf[0], fold + FOLD_OFF[6], actB, B, 256, 512);
    // fc1: 512->512
    hipLaunchKernelGGL(fc_q_k, dim3(cdiv((long long)B * 512, 256)), dim3(256), 0, stream,
                       actB, tf[1], fold + FOLD_OFF[7], actA, B, 512, 512);
    // fc2 + tensor norm
    hipLaunchKernelGGL(fc_out_k, dim3(cdiv((long long)B * 10, 256)), dim3(256), 0, stream,
                       actA, tf[2], scales + 8, tn_w, tn_b, tn_m, tn_v,
                       (float*)d_out, B, 512, 10);
}

// Round 3
// 3493.268 us; speedup vs baseline: 5.5116x; 2.1270x over previous
//
#include <hip/hip_runtime.h>
#include <stdint.h>

#define EPSF 1e-4f

// ---------------- workspace layout (bytes) ----------------
#define OFF_SCALES  0           // 16 floats: slots 0..5 conv, 6..8 fc
#define OFF_FOLD    1024        // folded BN params (A then B per layer), floats
#define OFF_W       32768       // ternary weights
#define OFF_TC0     (OFF_W + 0)          // 64*9*4    = 2304
#define OFF_TC1     (OFF_W + 2304)       // 64*9*64   = 36864
#define OFF_TC2     (OFF_W + 39168)      // 128*9*64  = 73728
#define OFF_TC3     (OFF_W + 112896)     // 128*9*128 = 147456
#define OFF_TC4     (OFF_W + 260352)     // 256*9*128 = 294912
#define OFF_TC5     (OFF_W + 555264)     // 256*9*256 = 589824
#define OFF_TF0     (OFF_W + 1145088)    // 512*256   = 131072
#define OFF_TF1     (OFF_W + 1276160)    // 512*512   = 262144
#define OFF_TF2     (OFF_W + 1538304)    // 10*512    = 5120
#define OFF_ACT_A   2097152
#define OFF_ACT_B   60817408

static const int FOLD_OFF[8] = {0, 128, 256, 512, 768, 1280, 1792, 2816};

__device__ __forceinline__ int dot4(int a, int b, int c) {
#if __has_builtin(__builtin_amdgcn_sdot4)
    return __builtin_amdgcn_sdot4(a, b, c, false);
#else
    c += (int)(int8_t)(a) * (int)(int8_t)(b);
    c += (int)(int8_t)(a >> 8)  * (int)(int8_t)(b >> 8);
    c += (int)(int8_t)(a >> 16) * (int)(int8_t)(b >> 16);
    c += (int)(int8_t)(a >> 24) * (int)(int8_t)(b >> 24);
    return c;
#endif
}

// ---------------- prep kernels ----------------
__global__ void zero_scales_k(float* s) {
    if (threadIdx.x < 16) s[threadIdx.x] = 0.f;
}

__global__ void absmax_k(const float* __restrict__ w, int n, float* slot) {
    __shared__ float red[256];
    float m = 0.f;
    for (int i = blockIdx.x * blockDim.x + threadIdx.x; i < n; i += gridDim.x * blockDim.x)
        m = fmaxf(m, fabsf(w[i]));
    red[threadIdx.x] = m;
    __syncthreads();
    for (int s2 = 128; s2 > 0; s2 >>= 1) {
        if ((int)threadIdx.x < s2) red[threadIdx.x] = fmaxf(red[threadIdx.x], red[threadIdx.x + s2]);
        __syncthreads();
    }
    if (threadIdx.x == 0) atomicMax((unsigned int*)slot, __float_as_uint(red[0]));
}

// conv weight ternarize + transpose OIHW -> [co][ky][kx][ci_pad]
__global__ void tern_conv_k(const float* __restrict__ w, const float* __restrict__ slot,
                            int8_t* __restrict__ t, int CO, int CI, int CIp) {
    int idx = blockIdx.x * blockDim.x + threadIdx.x;
    int n = CO * 9 * CIp;
    if (idx >= n) return;
    int ci = idx % CIp;
    int t1 = idx / CIp;
    int kxy = t1 % 9;
    int co = t1 / 9;
    float val = 0.f;
    if (ci < CI) val = w[((size_t)co * CI + ci) * 9 + kxy];
    float q = fminf(fmaxf(rintf(val / slot[0]), -1.f), 1.f);
    t[idx] = (int8_t)q;
}

__global__ void tern_fc_k(const float* __restrict__ w, int n, const float* __restrict__ slot,
                          int8_t* __restrict__ t) {
    int i = blockIdx.x * blockDim.x + threadIdx.x;
    if (i >= n) return;
    float q = fminf(fmaxf(rintf(w[i] / slot[0]), -1.f), 1.f);
    t[i] = (int8_t)q;
}

__global__ void bnfold_k(const float* __restrict__ slot, const float* __restrict__ g,
                         const float* __restrict__ b, const float* __restrict__ m,
                         const float* __restrict__ v, float s_in, int n,
                         float* __restrict__ fold) {
    int i = blockIdx.x * blockDim.x + threadIdx.x;
    if (i >= n) return;
    float sc = g[i] / sqrtf(v[i] + EPSF);
    fold[i] = s_in * slot[0] * sc;
    fold[n + i] = b[i] - m[i] * sc;
}

// input quant: NCHW float -> NHWC4 int8 (channel 3 = 0 pad)
__global__ void quant_in_k(const float* __restrict__ x, int* __restrict__ o, int B) {
    int idx = blockIdx.x * blockDim.x + threadIdx.x;
    int n = B * 1024;
    if (idx >= n) return;
    int p = idx & 1023;
    int b = idx >> 10;
    unsigned pk = 0;
#pragma unroll
    for (int c = 0; c < 3; ++c) {
        float q = rintf(x[((size_t)b * 3 + c) * 1024 + p] * 128.f);
        q = fminf(fmaxf(q, -127.f), 127.f);
        pk |= ((unsigned)((int)q & 0xff)) << (8 * c);
    }
    o[idx] = (int)pk;
}

// ---------------- conv kernels (LDS-staged, register-tiled dot4) ----------------
// Common compute core: acts staged in LDS with per-position pitch PITCH (=CI+16 for
// bank spread), weights [co][kxy][ci] in global (wave-uniform addr -> s_load),
// each lane: 8 co x J positions.

template<int CI, int PITCH, int IH, int IW, int CO, int OH, int OW, int MAXR, int J>
__global__ __launch_bounds__(256) void conv_rows_k(
        const int8_t* __restrict__ act, const int8_t* __restrict__ wt,
        const float* __restrict__ fold, int8_t* __restrict__ out) {
    constexpr int NPOS = OH * OW;
    constexpr int NBLK = (NPOS + 255) / 256;
    __shared__ __align__(16) int8_t lds[MAXR * IW * PITCH];

    int b = blockIdx.x / NBLK;
    int tile = blockIdx.x % NBLK;
    int pos0 = tile * 256;
    int r0 = pos0 / OW;
    int last = min(pos0 + 255, NPOS - 1);
    int r1 = last / OW + 2;          // last input row needed (<= IH-1)
    int R = r1 - r0 + 1;

    // stage input rows r0..r1 (contiguous in NHWC) into padded LDS
    const int8_t* src = act + ((size_t)b * IH + r0) * IW * CI;
    int npos_in = R * IW;
    for (int p = threadIdx.x; p < npos_in; p += 256) {
        if constexpr (CI == 4) {
            *(int*)&lds[p * PITCH] = *(const int*)(src + (size_t)p * 4);
        } else {
#pragma unroll
            for (int k = 0; k < CI / 16; ++k)
                *(int4*)&lds[p * PITCH + k * 16] = *(const int4*)(src + (size_t)p * CI + k * 16);
        }
    }
    __syncthreads();

    int wv = __builtin_amdgcn_readfirstlane((int)(threadIdx.x >> 6));
    int lane = threadIdx.x & 63;

    int baseo[J];
    bool val[J];
#pragma unroll
    for (int j = 0; j < J; ++j) {
        int pos = pos0 + lane + 64 * j;
        val[j] = pos < NPOS;
        int pc = val[j] ? pos : NPOS - 1;
        int oy = pc / OW, ox = pc % OW;
        baseo[j] = ((oy - r0) * IW + ox) * PITCH;
    }

    for (int pass = 0; pass < CO / 32; ++pass) {
        int co0 = pass * 32 + wv * 8;
        int acc[8][J];
#pragma unroll
        for (int c = 0; c < 8; ++c)
#pragma unroll
            for (int j = 0; j < J; ++j) acc[c][j] = 0;

#pragma unroll
        for (int ky = 0; ky < 3; ++ky) {
#pragma unroll
            for (int kx = 0; kx < 3; ++kx) {
                const int8_t* wrow = wt + ((size_t)co0 * 9 + ky * 3 + kx) * CI;
                if constexpr (CI == 4) {
                    int wv4[8];
#pragma unroll
                    for (int c = 0; c < 8; ++c)
                        wv4[c] = *(const int*)(wrow + (size_t)c * 9 * 4);
#pragma unroll
                    for (int j = 0; j < J; ++j) {
                        int a = *(const int*)&lds[baseo[j] + (ky * IW + kx) * PITCH];
#pragma unroll
                        for (int c = 0; c < 8; ++c)
                            acc[c][j] = dot4(a, wv4[c], acc[c][j]);
                    }
                } else {
#pragma unroll
                    for (int c16 = 0; c16 < CI / 16; ++c16) {
                        int4 wv4[8];
#pragma unroll
                        for (int c = 0; c < 8; ++c)
                            wv4[c] = *(const int4*)(wrow + (size_t)c * 9 * CI + c16 * 16);
#pragma unroll
                        for (int j = 0; j < J; ++j) {
                            int4 a = *(const int4*)&lds[baseo[j] + (ky * IW + kx) * PITCH + c16 * 16];
#pragma unroll
                            for (int c = 0; c < 8; ++c) {
                                acc[c][j] = dot4(a.x, wv4[c].x, acc[c][j]);
                                acc[c][j] = dot4(a.y, wv4[c].y, acc[c][j]);
                                acc[c][j] = dot4(a.z, wv4[c].z, acc[c][j]);
                                acc[c][j] = dot4(a.w, wv4[c].w, acc[c][j]);
                            }
                        }
                    }
                }
            }
        }

        float Af[8], Bf[8];
#pragma unroll
        for (int c = 0; c < 8; ++c) {
            Af[c] = fold[co0 + c];
            Bf[c] = fold[CO + co0 + c];
        }
#pragma unroll
        for (int j = 0; j < J; ++j) {
            if (!val[j]) continue;
            int pos = pos0 + lane + 64 * j;
            unsigned lo = 0, hi = 0;
#pragma unroll
            for (int c = 0; c < 4; ++c) {
                int v0 = (int)fminf(fmaxf(rintf((float)acc[c][j] * Af[c] + Bf[c]), -1.f), 1.f);
                int v1 = (int)fminf(fmaxf(rintf((float)acc[c + 4][j] * Af[c + 4] + Bf[c + 4]), -1.f), 1.f);
                lo |= ((unsigned)(v0 & 0xff)) << (8 * c);
                hi |= ((unsigned)(v1 & 0xff)) << (8 * c);
            }
            *(int2*)&out[((size_t)b * NPOS + pos) * CO + co0] = make_int2((int)lo, (int)hi);
        }
    }
}

template<int CI, int PITCH, int IH, int IW, int CO, int OH, int OW, int NIMG, int J>
__global__ __launch_bounds__(256) void conv_img_k(
        const int8_t* __restrict__ act, const int8_t* __restrict__ wt,
        const float* __restrict__ fold, int8_t* __restrict__ out) {
    constexpr int NPOS1 = OH * OW;
    constexpr int NPOS = NIMG * NPOS1;
    constexpr int INP1 = IH * IW;
    __shared__ __align__(16) int8_t lds[NIMG * INP1 * PITCH];

    int b0 = blockIdx.x * NIMG;
    const int8_t* src = act + (size_t)b0 * INP1 * CI;
    for (int p = threadIdx.x; p < NIMG * INP1; p += 256) {
#pragma unroll
        for (int k = 0; k < CI / 16; ++k)
            *(int4*)&lds[p * PITCH + k * 16] = *(const int4*)(src + (size_t)p * CI + k * 16);
    }
    __syncthreads();

    int wv = __builtin_amdgcn_readfirstlane((int)(threadIdx.x >> 6));
    int lane = threadIdx.x & 63;

    int baseo[J];
    bool val[J];
#pragma unroll
    for (int j = 0; j < J; ++j) {
        int pos = lane + 64 * j;
        val[j] = pos < NPOS;
        int pc = val[j] ? pos : NPOS - 1;
        int img = pc / NPOS1, p = pc % NPOS1;
        int oy = p / OW, ox = p % OW;
        baseo[j] = (img * INP1 + oy * IW + ox) * PITCH;
    }

    for (int pass = 0; pass < CO / 32; ++pass) {
        int co0 = pass * 32 + wv * 8;
        int acc[8][J];
#pragma unroll
        for (int c = 0; c < 8; ++c)
#pragma unroll
            for (int j = 0; j < J; ++j) acc[c][j] = 0;

#pragma unroll
        for (int ky = 0; ky < 3; ++ky) {
#pragma unroll
            for (int kx = 0; kx < 3; ++kx) {
                const int8_t* wrow = wt + ((size_t)co0 * 9 + ky * 3 + kx) * CI;
#pragma unroll
                for (int c16 = 0; c16 < CI / 16; ++c16) {
                    int4 wv4[8];
#pragma unroll
                    for (int c = 0; c < 8; ++c)
                        wv4[c] = *(const int4*)(wrow + (size_t)c * 9 * CI + c16 * 16);
#pragma unroll
                    for (int j = 0; j < J; ++j) {
                        int4 a = *(const int4*)&lds[baseo[j] + (ky * IW + kx) * PITCH + c16 * 16];
#pragma unroll
                        for (int c = 0; c < 8; ++c) {
                            acc[c][j] = dot4(a.x, wv4[c].x, acc[c][j]);
                            acc[c][j] = dot4(a.y, wv4[c].y, acc[c][j]);
                            acc[c][j] = dot4(a.z, wv4[c].z, acc[c][j]);
                            acc[c][j] = dot4(a.w, wv4[c].w, acc[c][j]);
                        }
                    }
                }
            }
        }

        float Af[8], Bf[8];
#pragma unroll
        for (int c = 0; c < 8; ++c) {
            Af[c] = fold[co0 + c];
            Bf[c] = fold[CO + co0 + c];
        }
#pragma unroll
        for (int j = 0; j < J; ++j) {
            if (!val[j]) continue;
            int pos = lane + 64 * j;
            int img = pos / NPOS1, p = pos % NPOS1;
            unsigned lo = 0, hi = 0;
#pragma unroll
            for (int c = 0; c < 4; ++c) {
                int v0 = (int)fminf(fmaxf(rintf((float)acc[c][j] * Af[c] + Bf[c]), -1.f), 1.f);
                int v1 = (int)fminf(fmaxf(rintf((float)acc[c + 4][j] * Af[c + 4] + Bf[c + 4]), -1.f), 1.f);
                lo |= ((unsigned)(v0 & 0xff)) << (8 * c);
                hi |= ((unsigned)(v1 & 0xff)) << (8 * c);
            }
            *(int2*)&out[((size_t)(b0 + img) * NPOS1 + p) * CO + co0] = make_int2((int)lo, (int)hi);
        }
    }
}

// ---------------- pool ----------------
__global__ void pool_k(const int8_t* __restrict__ a, int8_t* __restrict__ o,
                       int B, int C, int IH, int IW, int OH, int OW) {
    int idx = blockIdx.x * blockDim.x + threadIdx.x;
    int c4n = C >> 2;
    int total = B * OH * OW * c4n;
    if (idx >= total) return;
    int c4 = idx % c4n;
    int t1 = idx / c4n;
    int ox = t1 % OW;
    int t2 = t1 / OW;
    int oy = t2 % OH;
    int b = t2 / OH;
    const int8_t* p = a + (((size_t)b * IH + 2 * oy) * IW + 2 * ox) * C + 4 * c4;
    int w0 = *(const int*)p;
    int w1 = *(const int*)(p + C);
    int w2 = *(const int*)(p + (size_t)IW * C);
    int w3 = *(const int*)(p + (size_t)IW * C + C);
    unsigned r = 0;
#pragma unroll
    for (int k = 0; k < 4; ++k) {
        int x0 = (int)(int8_t)(w0 >> (8 * k));
        int x1 = (int)(int8_t)(w1 >> (8 * k));
        int x2 = (int)(int8_t)(w2 >> (8 * k));
        int x3 = (int)(int8_t)(w3 >> (8 * k));
        int mx = max(max(x0, x1), max(x2, x3));
        r |= ((unsigned)(mx & 0xff)) << (8 * k);
    }
    *(int*)(o + (((size_t)b * OH + oy) * OW + ox) * C + 4 * c4) = (int)r;
}

// ---------------- FC kernels ----------------
// 8-output register tile per thread, b128 loads, dot4
__global__ __launch_bounds__(256) void fc_q_k(
        const int8_t* __restrict__ a, const int8_t* __restrict__ t,
        const float* __restrict__ fold, int8_t* __restrict__ out,
        int B, int I, int OG, int O) {
    int idx = blockIdx.x * blockDim.x + threadIdx.x;
    if (idx >= B * OG) return;
    int og = idx % OG;
    int b = idx / OG;
    const int8_t* ar = a + (size_t)b * I;
    const int8_t* wr = t + (size_t)og * 8 * I;
    int acc[8] = {0, 0, 0, 0, 0, 0, 0, 0};
    for (int i = 0; i < I; i += 16) {
        int4 av = *(const int4*)(ar + i);
#pragma unroll
        for (int c = 0; c < 8; ++c) {
            int4 wv4 = *(const int4*)(wr + (size_t)c * I + i);
            acc[c] = dot4(av.x, wv4.x, acc[c]);
            acc[c] = dot4(av.y, wv4.y, acc[c]);
            acc[c] = dot4(av.z, wv4.z, acc[c]);
            acc[c] = dot4(av.w, wv4.w, acc[c]);
        }
    }
    int o0 = og * 8;
    unsigned lo = 0, hi = 0;
#pragma unroll
    for (int c = 0; c < 4; ++c) {
        int v0 = (int)fminf(fmaxf(rintf((float)acc[c] * fold[o0 + c] + fold[O + o0 + c]), -1.f), 1.f);
        int v1 = (int)fminf(fmaxf(rintf((float)acc[c + 4] * fold[o0 + c + 4] + fold[O + o0 + c + 4]), -1.f), 1.f);
        lo |= ((unsigned)(v0 & 0xff)) << (8 * c);
        hi |= ((unsigned)(v1 & 0xff)) << (8 * c);
    }
    *(int2*)&out[(size_t)b * O + o0] = make_int2((int)lo, (int)hi);
}

__global__ void fc_out_k(const int8_t* __restrict__ a, const int8_t* __restrict__ t,
                         const float* __restrict__ slot,
                         const float* __restrict__ tw, const float* __restrict__ tb,
                         const float* __restrict__ tm, const float* __restrict__ tv,
                         float* __restrict__ out, int B, int I, int O) {
    int idx = blockIdx.x * blockDim.x + threadIdx.x;
    if (idx >= B * O) return;
    int o = idx % O;
    int b = idx / O;
    const int* ar = (const int*)(a + (size_t)b * I);
    const int* tr = (const int*)(t + (size_t)o * I);
    int acc = 0;
    for (int i = 0; i < (I >> 2); ++i) acc = dot4(ar[i], tr[i], acc);
    float sc = tw[0] / sqrtf(tv[0] + EPSF);
    out[idx] = ((float)acc * slot[0] - tm[0]) * sc + tb[0];
}

static inline unsigned cdiv(long long a, int b) { return (unsigned)((a + b - 1) / b); }

extern "C" void kernel_launch(void* const* d_in, const int* in_sizes, int n_in,
                              void* d_out, int out_size, void* d_ws, size_t ws_size,
                              hipStream_t stream) {
    const float* x = (const float*)d_in[0];
    const float* cw[6]; const float* bng[6]; const float* bnb[6];
    const float* bnm[6]; const float* bnv[6];
    for (int l = 0; l < 6; ++l) {
        cw[l]  = (const float*)d_in[1 + 5 * l + 0];
        bng[l] = (const float*)d_in[1 + 5 * l + 1];
        bnb[l] = (const float*)d_in[1 + 5 * l + 2];
        bnm[l] = (const float*)d_in[1 + 5 * l + 3];
        bnv[l] = (const float*)d_in[1 + 5 * l + 4];
    }
    const float* fws[3] = { (const float*)d_in[31], (const float*)d_in[32], (const float*)d_in[33] };
    const float* fbn[2][4] = {
        { (const float*)d_in[34], (const float*)d_in[35], (const float*)d_in[36], (const float*)d_in[37] },
        { (const float*)d_in[38], (const float*)d_in[39], (const float*)d_in[40], (const float*)d_in[41] } };
    const float* tn_w = (const float*)d_in[42];
    const float* tn_b = (const float*)d_in[43];
    const float* tn_m = (const float*)d_in[44];
    const float* tn_v = (const float*)d_in[45];

    char* ws = (char*)d_ws;
    float* scales = (float*)(ws + OFF_SCALES);
    float* fold = (float*)(ws + OFF_FOLD);
    int8_t* tc[6] = { (int8_t*)(ws + OFF_TC0), (int8_t*)(ws + OFF_TC1), (int8_t*)(ws + OFF_TC2),
                      (int8_t*)(ws + OFF_TC3), (int8_t*)(ws + OFF_TC4), (int8_t*)(ws + OFF_TC5) };
    int8_t* tf[3] = { (int8_t*)(ws + OFF_TF0), (int8_t*)(ws + OFF_TF1), (int8_t*)(ws + OFF_TF2) };
    int8_t* actA = (int8_t*)(ws + OFF_ACT_A);
    int8_t* actB = (int8_t*)(ws + OFF_ACT_B);

    const int B = in_sizes[0] / 3072;
    const int conv_wn[6] = { 64*3*9, 64*64*9, 128*64*9, 128*128*9, 256*128*9, 256*256*9 };
    const int conv_CI[6]  = { 3, 64, 64, 128, 128, 256 };
    const int conv_CIp[6] = { 4, 64, 64, 128, 128, 256 };
    const int conv_CO[6]  = { 64, 64, 128, 128, 256, 256 };
    const int fc_wn[3] = { 512*256, 512*512, 10*512 };

    hipLaunchKernelGGL(zero_scales_k, dim3(1), dim3(16), 0, stream, scales);
    for (int l = 0; l < 6; ++l) {
        unsigned gb = cdiv(conv_wn[l], 256); if (gb > 1024) gb = 1024;
        hipLaunchKernelGGL(absmax_k, dim3(gb), dim3(256), 0, stream, cw[l], conv_wn[l], scales + l);
    }
    for (int l = 0; l < 3; ++l) {
        unsigned gb = cdiv(fc_wn[l], 256); if (gb > 1024) gb = 1024;
        hipLaunchKernelGGL(absmax_k, dim3(gb), dim3(256), 0, stream, fws[l], fc_wn[l], scales + 6 + l);
    }
    for (int l = 0; l < 6; ++l) {
        int n = conv_CO[l] * 9 * conv_CIp[l];
        hipLaunchKernelGGL(tern_conv_k, dim3(cdiv(n, 256)), dim3(256), 0, stream,
                           cw[l], scales + l, tc[l], conv_CO[l], conv_CI[l], conv_CIp[l]);
    }
    for (int l = 0; l < 3; ++l)
        hipLaunchKernelGGL(tern_fc_k, dim3(cdiv(fc_wn[l], 256)), dim3(256), 0, stream,
                           fws[l], fc_wn[l], scales + 6 + l, tf[l]);
    for (int l = 0; l < 6; ++l)
        hipLaunchKernelGGL(bnfold_k, dim3(1), dim3(256), 0, stream,
                           scales + l, bng[l], bnb[l], bnm[l], bnv[l],
                           l == 0 ? 0.0078125f : 1.0f, conv_CO[l], fold + FOLD_OFF[l]);
    for (int l = 0; l < 2; ++l)
        hipLaunchKernelGGL(bnfold_k, dim3(2), dim3(256), 0, stream,
                           scales + 6 + l, fbn[l][0], fbn[l][1], fbn[l][2], fbn[l][3],
                           1.0f, 512, fold + FOLD_OFF[6 + l]);

    hipLaunchKernelGGL(quant_in_k, dim3(cdiv((long long)B * 1024, 256)), dim3(256), 0, stream,
                       x, (int*)actA, B);

    // conv0: CI4, 32->30, CO64; 900 pos -> 4 blocks/img
    hipLaunchKernelGGL((conv_rows_k<4, 4, 32, 32, 64, 30, 30, 12, 4>),
                       dim3(B * 4), dim3(256), 0, stream, actA, tc[0], fold + FOLD_OFF[0], actB);
    // conv1: CI64, 30->28, CO64; 784 pos -> 4 blocks/img
    hipLaunchKernelGGL((conv_rows_k<64, 80, 30, 30, 64, 28, 28, 12, 4>),
                       dim3(B * 4), dim3(256), 0, stream, actB, tc[1], fold + FOLD_OFF[1], actA);
    // pool 28->14 (64 ch)
    hipLaunchKernelGGL(pool_k, dim3(cdiv((long long)B * 14 * 14 * 16, 256)), dim3(256), 0, stream,
                       actA, actB, B, 64, 28, 28, 14, 14);
    // conv2: CI64, 14->12, CO128; 1 img/block, J=3
    hipLaunchKernelGGL((conv_img_k<64, 80, 14, 14, 128, 12, 12, 1, 3>),
                       dim3(B), dim3(256), 0, stream, actB, tc[2], fold + FOLD_OFF[2], actA);
    // conv3: CI128, 12->10, CO128; 1 img/block, J=2
    hipLaunchKernelGGL((conv_img_k<128, 144, 12, 12, 128, 10, 10, 1, 2>),
                       dim3(B), dim3(256), 0, stream, actA, tc[3], fold + FOLD_OFF[3], actB);
    // pool 10->5 (128 ch)
    hipLaunchKernelGGL(pool_k, dim3(cdiv((long long)B * 5 * 5 * 32, 256)), dim3(256), 0, stream,
                       actB, actA, B, 128, 10, 10, 5, 5);
    // conv4: CI128, 5->3, CO256; 8 img/block, J=2
    hipLaunchKernelGGL((conv_img_k<128, 144, 5, 5, 256, 3, 3, 8, 2>),
                       dim3(B / 8), dim3(256), 0, stream, actA, tc[4], fold + FOLD_OFF[4], actB);
    // conv5 == FC: I = 3*3*256 = 2304 (im2col is identity), O=256
    hipLaunchKernelGGL(fc_q_k, dim3(cdiv((long long)B * 32, 256)), dim3(256), 0, stream,
                       actB, tc[5], fold + FOLD_OFF[5], actA, B, 2304, 32, 256);
    // fc0: 256->512
    hipLaunchKernelGGL(fc_q_k, dim3(cdiv((long long)B * 64, 256)), dim3(256), 0, stream,
                       actA, tf[0], fold + FOLD_OFF[6], actB, B, 256, 64, 512);
    // fc1: 512->512
    hipLaunchKernelGGL(fc_q_k, dim3(cdiv((long long)B * 64, 256)), dim3(256), 0, stream,
                       actB, tf[1], fold + FOLD_OFF[7], actA, B, 512, 64, 512);
    // fc2 + tensor norm
    hipLaunchKernelGGL(fc_out_k, dim3(cdiv((long long)B * 10, 256)), dim3(256), 0, stream,
                       actA, tf[2], scales + 8, tn_w, tn_b, tn_m, tn_v,
                       (float*)d_out, B, 512, 10);
}

// Round 4
// 428.763 us; speedup vs baseline: 44.9046x; 8.1473x over previous
//
#include <hip/hip_runtime.h>
#include <stdint.h>

#define EPSF 1e-4f

typedef int v4i __attribute__((ext_vector_type(4)));

// ---------------- workspace layout (bytes) ----------------
#define OFF_SCALES 0            // 16 floats (slots 0..5 conv, 6..8 fc)
#define OFF_FOLD   1024         // folded BN params
#define OFF_W      32768        // B-fragment weights (MFMA lane order)
#define OFF_TF2    (OFF_W + 1548288)   // fc2 ternary [10][512]
#define OFF_ACT_A  2097152
#define OFF_ACT_B  60817408

static const int FOLD_OFF_H[8] = {0,128,256,512,768,1280,1792,2816};
__device__ __constant__ int FOLD_OFF_D[8] = {0,128,256,512,768,1280,1792,2816};

// per-layer B-frag prep tables: l0..5 = conv0..5, l6=fc0, l7=fc1
__device__ __constant__ int PREP_MODE[8] = {0,1,1,1,1,1,2,2};
__device__ __constant__ int PREP_CO[8]   = {64,64,128,128,256,256,512,512};
__device__ __constant__ int PREP_CI[8]   = {3,64,64,128,128,256,256,512};
__device__ __constant__ int PREP_KC[8]   = {1,1,1,2,2,4,1,1};
__device__ __constant__ int PREP_NB[8]   = {12288,36864,73728,147456,294912,589824,131072,262144};
__device__ __constant__ int PREP_OFF[8]  = {0,12288,49152,122880,270336,565248,1155072,1286144};

// ---------------- prep kernels ----------------
__global__ void zero_scales_k(float* s) { if (threadIdx.x < 16) s[threadIdx.x] = 0.f; }

struct AbsArgs { const float* w[9]; int n[9]; };
__global__ void absmax_all_k(AbsArgs a, float* scales) {
    __shared__ float red[256];
    int l = blockIdx.x >> 4;
    int sb = blockIdx.x & 15;
    const float* w = a.w[l];
    int n = a.n[l];
    float m = 0.f;
    for (int i = sb * 256 + threadIdx.x; i < n; i += 16 * 256)
        m = fmaxf(m, fabsf(w[i]));
    red[threadIdx.x] = m;
    __syncthreads();
    for (int s2 = 128; s2 > 0; s2 >>= 1) {
        if ((int)threadIdx.x < s2) red[threadIdx.x] = fmaxf(red[threadIdx.x], red[threadIdx.x + s2]);
        __syncthreads();
    }
    if (threadIdx.x == 0) atomicMax((unsigned int*)(scales + l), __float_as_uint(red[0]));
}

__global__ void tern_fc_k(const float* __restrict__ w, int n, const float* __restrict__ slot,
                          int8_t* __restrict__ t) {
    int i = blockIdx.x * blockDim.x + threadIdx.x;
    if (i >= n) return;
    float q = fminf(fmaxf(rintf(w[i] / slot[0]), -1.f), 1.f);
    t[i] = (int8_t)q;
}

// B-fragment prep: dest byte idx = ((s*COT + ct)*64 + lane)*16 + jb
// lane = quad*16 + n ; value = W[co = ct*16+n][k = s*64 + quad*16 + jb]
struct PrepArgs { const float* w[8]; };
__global__ void bprep_all_k(PrepArgs pa, const float* __restrict__ scales,
                            int8_t* __restrict__ dst) {
    int l = blockIdx.y;
    int idx = blockIdx.x * 256 + threadIdx.x;
    if (idx >= PREP_NB[l]) return;
    const float* w = pa.w[l];
    float s = scales[l];
    int jb = idx & 15;
    int lane = (idx >> 4) & 63;
    int fct = idx >> 10;
    int quad = lane >> 4, n = lane & 15;
    int COT = PREP_CO[l] >> 4;
    int ct = fct & (COT - 1);
    int st = fct >> (31 - __clz(COT));
    int co = ct * 16 + n;
    float val;
    int md = PREP_MODE[l];
    if (md == 0) {
        // conv0, CI padded to 16: k = quad*16+jb -> dx=quad, ci=jb
        int ky = st, dx = quad, ci = jb;
        val = (dx < 3 && ci < 3) ? w[(co * 3 + ci) * 9 + ky * 3 + dx] : 0.f;
    } else if (md == 1) {
        int KC = PREP_KC[l], CI = PREP_CI[l];
        int kxy = st / KC, kc = st - kxy * KC;
        int ci = kc * 64 + quad * 16 + jb;
        val = w[(co * CI + ci) * 9 + kxy];
    } else {
        int CI = PREP_CI[l];
        int i = st * 64 + quad * 16 + jb;
        val = w[co * CI + i];
    }
    float q = fminf(fmaxf(rintf(val / s), -1.f), 1.f);
    dst[PREP_OFF[l] + idx] = (int8_t)q;
}

struct BnArgs { const float* g[8]; const float* b[8]; const float* m[8]; const float* v[8]; };
__global__ void bnfold_all_k(BnArgs ba, const float* __restrict__ scales,
                             float* __restrict__ fold) {
    int l = blockIdx.y;
    int i = blockIdx.x * 256 + threadIdx.x;
    int CO = PREP_CO[l];
    if (i >= CO) return;
    float sc = ba.g[l][i] / sqrtf(ba.v[l][i] + EPSF);
    float s_in = (l == 0) ? 0.0078125f : 1.0f;
    fold[FOLD_OFF_D[l] + i] = s_in * scales[l] * sc;
    fold[FOLD_OFF_D[l] + CO + i] = ba.b[l][i] - ba.m[l][i] * sc;
}

// input quant: NCHW float -> NHWC16 int8 (channels 3..15 zero)
__global__ void quant_in_k(const float* __restrict__ x, int4* __restrict__ o, int B) {
    int idx = blockIdx.x * blockDim.x + threadIdx.x;
    if (idx >= B * 1024) return;
    int p = idx & 1023;
    int b = idx >> 10;
    unsigned pk = 0;
#pragma unroll
    for (int c = 0; c < 3; ++c) {
        float q = rintf(x[((size_t)b * 3 + c) * 1024 + p] * 128.f);
        q = fminf(fmaxf(q, -127.f), 127.f);
        pk |= ((unsigned)((int)q & 0xff)) << (8 * c);
    }
    o[idx] = make_int4((int)pk, 0, 0, 0);
}

// ---------------- MFMA implicit-GEMM conv/FC ----------------
// A-frag: lane m=lane&15 (position), quad=lane>>4: 16B global load at
//   pos_base + (ky*IW+kx)*CI + kc*64 + quad*16   (coalesced)
// B-frag: prepped, addr = base + (s*COT+ct)*1024 + lane*16 (coalesced)
// C/D: col=lane&15 (co), row=quad*4+reg (position). Epilogue through
// wave-private LDS tile (pitch W+8 -> conflict-free byte writes).
template<int CO, int NSTEP, int KC, int KXN, int CI, int IH, int IW, int OW,
         int NPOS1, int J, int NCT, int COG>
__global__ __launch_bounds__(256, 4) void mfconv_k(
        const int8_t* __restrict__ act, const int8_t* __restrict__ bf,
        const float* __restrict__ fold, int8_t* __restrict__ out, int NPOS) {
    constexpr int W = 16 * NCT, P = W + 8, R = 16 * J;
    constexpr int COT = CO / 16;
    __shared__ int8_t lds[4][R * P];
    int lane = threadIdx.x & 63;
    int wid = threadIdx.x >> 6;
    int w = blockIdx.x * 4 + wid;
    int PG = NPOS / (16 * J);
    if (w >= PG * COG) return;
    int pg = w % PG, cg = w / PG;
    int m = lane & 15, quad = lane >> 4;
    int pos0 = pg * (16 * J);

    const int8_t* ab[J];
#pragma unroll
    for (int j = 0; j < J; ++j) {
        int pos = pos0 + j * 16 + m;
        int img = pos / NPOS1, p = pos - img * NPOS1;
        int oy = p / OW, ox = p - oy * OW;
        ab[j] = act + (size_t)((img * IH + oy) * IW + ox) * CI + quad * 16;
    }
    const int8_t* bb = bf + (size_t)(cg * NCT) * 1024 + lane * 16;

    v4i acc[J][NCT] = {};
#pragma unroll
    for (int s = 0; s < NSTEP; ++s) {
        int kxy = s / KC, kc = s - kxy * KC;
        int ky = kxy / KXN, kx = kxy - ky * KXN;
        int off = (ky * IW + kx) * CI + kc * 64;
        v4i Bv[NCT];
#pragma unroll
        for (int ct = 0; ct < NCT; ++ct)
            Bv[ct] = *(const v4i*)(bb + (size_t)(s * COT + ct) * 1024);
#pragma unroll
        for (int j = 0; j < J; ++j) {
            v4i Av = *(const v4i*)(ab[j] + off);
#pragma unroll
            for (int ct = 0; ct < NCT; ++ct)
                acc[j][ct] = __builtin_amdgcn_mfma_i32_16x16x64_i8(Av, Bv[ct], acc[j][ct], 0, 0, 0);
        }
    }

    // epilogue: BN + 2-bit quant -> LDS byte transpose -> coalesced store
    int8_t* L = lds[wid];
#pragma unroll
    for (int ct = 0; ct < NCT; ++ct) {
        int co = (cg * NCT + ct) * 16 + m;
        float Af = fold[co], Bf = fold[CO + co];
#pragma unroll
        for (int j = 0; j < J; ++j) {
#pragma unroll
            for (int r = 0; r < 4; ++r) {
                float h = (float)acc[j][ct][r] * Af + Bf;
                int q = (int)fminf(fmaxf(rintf(h), -1.f), 1.f);
                L[(j * 16 + quad * 4 + r) * P + ct * 16 + m] = (int8_t)q;
            }
        }
    }
    constexpr int CH = (R * W / 8) / 64;
#pragma unroll
    for (int t = 0; t < CH; ++t) {
        int gid = t * 64 + lane;
        int row = gid / (W / 8), c8 = gid - row * (W / 8);
        int2 vv = *(const int2*)&L[row * P + c8 * 8];
        *(int2*)&out[(size_t)(pos0 + row) * CO + cg * W + c8 * 8] = vv;
    }
}

// ---------------- pool ----------------
__global__ void pool_k(const int8_t* __restrict__ a, int8_t* __restrict__ o,
                       int B, int C, int IH, int IW, int OH, int OW) {
    int idx = blockIdx.x * blockDim.x + threadIdx.x;
    int c4n = C >> 2;
    int total = B * OH * OW * c4n;
    if (idx >= total) return;
    int c4 = idx % c4n;
    int t1 = idx / c4n;
    int ox = t1 % OW;
    int t2 = t1 / OW;
    int oy = t2 % OH;
    int b = t2 / OH;
    const int8_t* p = a + (((size_t)b * IH + 2 * oy) * IW + 2 * ox) * C + 4 * c4;
    int w0 = *(const int*)p;
    int w1 = *(const int*)(p + C);
    int w2 = *(const int*)(p + (size_t)IW * C);
    int w3 = *(const int*)(p + (size_t)IW * C + C);
    unsigned r = 0;
#pragma unroll
    for (int k = 0; k < 4; ++k) {
        int x0 = (int)(int8_t)(w0 >> (8 * k));
        int x1 = (int)(int8_t)(w1 >> (8 * k));
        int x2 = (int)(int8_t)(w2 >> (8 * k));
        int x3 = (int)(int8_t)(w3 >> (8 * k));
        int mx = max(max(x0, x1), max(x2, x3));
        r |= ((unsigned)(mx & 0xff)) << (8 * k);
    }
    *(int*)(o + (((size_t)b * OH + oy) * OW + ox) * C + 4 * c4) = (int)r;
}

__device__ __forceinline__ int dot4(int a, int b, int c) {
#if __has_builtin(__builtin_amdgcn_sdot4)
    return __builtin_amdgcn_sdot4(a, b, c, false);
#else
    c += (int)(int8_t)(a) * (int)(int8_t)(b);
    c += (int)(int8_t)(a >> 8)  * (int)(int8_t)(b >> 8);
    c += (int)(int8_t)(a >> 16) * (int)(int8_t)(b >> 16);
    c += (int)(int8_t)(a >> 24) * (int)(int8_t)(b >> 24);
    return c;
#endif
}

// final FC + tensor norm -> float out (tiny: 1024x10x512)
__global__ void fc_out_k(const int8_t* __restrict__ a, const int8_t* __restrict__ t,
                         const float* __restrict__ slot,
                         const float* __restrict__ tw, const float* __restrict__ tb,
                         const float* __restrict__ tm, const float* __restrict__ tv,
                         float* __restrict__ out, int B, int I, int O) {
    int idx = blockIdx.x * blockDim.x + threadIdx.x;
    if (idx >= B * O) return;
    int o = idx % O;
    int b = idx / O;
    const int* ar = (const int*)(a + (size_t)b * I);
    const int* tr = (const int*)(t + (size_t)o * I);
    int acc = 0;
    for (int i = 0; i < (I >> 2); ++i) acc = dot4(ar[i], tr[i], acc);
    float sc = tw[0] / sqrtf(tv[0] + EPSF);
    out[idx] = ((float)acc * slot[0] - tm[0]) * sc + tb[0];
}

static inline unsigned cdiv(long long a, int b) { return (unsigned)((a + b - 1) / b); }

extern "C" void kernel_launch(void* const* d_in, const int* in_sizes, int n_in,
                              void* d_out, int out_size, void* d_ws, size_t ws_size,
                              hipStream_t stream) {
    const float* x = (const float*)d_in[0];
    const float* cw[6]; const float* bng[6]; const float* bnb[6];
    const float* bnm[6]; const float* bnv[6];
    for (int l = 0; l < 6; ++l) {
        cw[l]  = (const float*)d_in[1 + 5 * l + 0];
        bng[l] = (const float*)d_in[1 + 5 * l + 1];
        bnb[l] = (const float*)d_in[1 + 5 * l + 2];
        bnm[l] = (const float*)d_in[1 + 5 * l + 3];
        bnv[l] = (const float*)d_in[1 + 5 * l + 4];
    }
    const float* fw0 = (const float*)d_in[31];
    const float* fw1 = (const float*)d_in[32];
    const float* fw2 = (const float*)d_in[33];
    const float* fbn[2][4] = {
        { (const float*)d_in[34], (const float*)d_in[35], (const float*)d_in[36], (const float*)d_in[37] },
        { (const float*)d_in[38], (const float*)d_in[39], (const float*)d_in[40], (const float*)d_in[41] } };
    const float* tn_w = (const float*)d_in[42];
    const float* tn_b = (const float*)d_in[43];
    const float* tn_m = (const float*)d_in[44];
    const float* tn_v = (const float*)d_in[45];

    char* ws = (char*)d_ws;
    float* scales = (float*)(ws + OFF_SCALES);
    float* fold = (float*)(ws + OFF_FOLD);
    int8_t* bfw = (int8_t*)(ws + OFF_W);
    int8_t* tf2 = (int8_t*)(ws + OFF_TF2);
    int8_t* actA = (int8_t*)(ws + OFF_ACT_A);
    int8_t* actB = (int8_t*)(ws + OFF_ACT_B);

    const int B = in_sizes[0] / 3072;

    hipLaunchKernelGGL(zero_scales_k, dim3(1), dim3(16), 0, stream, scales);

    AbsArgs aa;
    aa.w[0]=cw[0]; aa.w[1]=cw[1]; aa.w[2]=cw[2]; aa.w[3]=cw[3]; aa.w[4]=cw[4]; aa.w[5]=cw[5];
    aa.w[6]=fw0; aa.w[7]=fw1; aa.w[8]=fw2;
    aa.n[0]=64*3*9; aa.n[1]=64*64*9; aa.n[2]=128*64*9; aa.n[3]=128*128*9;
    aa.n[4]=256*128*9; aa.n[5]=256*256*9; aa.n[6]=512*256; aa.n[7]=512*512; aa.n[8]=10*512;
    hipLaunchKernelGGL(absmax_all_k, dim3(144), dim3(256), 0, stream, aa, scales);

    hipLaunchKernelGGL(tern_fc_k, dim3(20), dim3(256), 0, stream, fw2, 5120, scales + 8, tf2);

    PrepArgs pp;
    pp.w[0]=cw[0]; pp.w[1]=cw[1]; pp.w[2]=cw[2]; pp.w[3]=cw[3]; pp.w[4]=cw[4]; pp.w[5]=cw[5];
    pp.w[6]=fw0; pp.w[7]=fw1;
    hipLaunchKernelGGL(bprep_all_k, dim3(2304, 8), dim3(256), 0, stream, pp, scales, bfw);

    BnArgs bb;
    for (int l = 0; l < 6; ++l) { bb.g[l]=bng[l]; bb.b[l]=bnb[l]; bb.m[l]=bnm[l]; bb.v[l]=bnv[l]; }
    for (int l = 0; l < 2; ++l) { bb.g[6+l]=fbn[l][0]; bb.b[6+l]=fbn[l][1]; bb.m[6+l]=fbn[l][2]; bb.v[6+l]=fbn[l][3]; }
    hipLaunchKernelGGL(bnfold_all_k, dim3(2, 8), dim3(256), 0, stream, bb, scales, fold);

    hipLaunchKernelGGL(quant_in_k, dim3(cdiv((long long)B * 1024, 256)), dim3(256), 0, stream,
                       x, (int4*)actA, B);

    // conv0: CI16(pad), 32->30, CO64, NSTEP=3 (ky), K=64 covers dx0..3 x ci
    {   int NPOS = B * 900, PG = NPOS / 64, blks = cdiv(PG * 1, 4);
        hipLaunchKernelGGL((mfconv_k<64, 3, 1, 1, 16, 32, 32, 30, 900, 4, 4, 1>),
                           dim3(blks), dim3(256), 0, stream, actA, bfw + 0, fold + FOLD_OFF_H[0], actB, NPOS); }
    // conv1: CI64, 30->28, CO64
    {   int NPOS = B * 784, PG = NPOS / 64, blks = cdiv(PG * 1, 4);
        hipLaunchKernelGGL((mfconv_k<64, 9, 1, 3, 64, 30, 30, 28, 784, 4, 4, 1>),
                           dim3(blks), dim3(256), 0, stream, actB, bfw + 12288, fold + FOLD_OFF_H[1], actA, NPOS); }
    // pool 28->14 (64ch)
    hipLaunchKernelGGL(pool_k, dim3(cdiv((long long)B * 14 * 14 * 16, 256)), dim3(256), 0, stream,
                       actA, actB, B, 64, 28, 28, 14, 14);
    // conv2: CI64, 14->12, CO128
    {   int NPOS = B * 144, PG = NPOS / 64, blks = cdiv(PG * 2, 4);
        hipLaunchKernelGGL((mfconv_k<128, 9, 1, 3, 64, 14, 14, 12, 144, 4, 4, 2>),
                           dim3(blks), dim3(256), 0, stream, actB, bfw + 49152, fold + FOLD_OFF_H[2], actA, NPOS); }
    // conv3: CI128, 12->10, CO128
    {   int NPOS = B * 100, PG = NPOS / 64, blks = cdiv(PG * 2, 4);
        hipLaunchKernelGGL((mfconv_k<128, 18, 2, 3, 128, 12, 12, 10, 100, 4, 4, 2>),
                           dim3(blks), dim3(256), 0, stream, actA, bfw + 122880, fold + FOLD_OFF_H[3], actB, NPOS); }
    // pool 10->5 (128ch)
    hipLaunchKernelGGL(pool_k, dim3(cdiv((long long)B * 5 * 5 * 32, 256)), dim3(256), 0, stream,
                       actB, actA, B, 128, 10, 10, 5, 5);
    // conv4: CI128, 5->3, CO256
    {   int NPOS = B * 9, PG = NPOS / 16, blks = cdiv(PG * 4, 4);
        hipLaunchKernelGGL((mfconv_k<256, 18, 2, 3, 128, 5, 5, 3, 9, 1, 4, 4>),
                           dim3(blks), dim3(256), 0, stream, actA, bfw + 270336, fold + FOLD_OFF_H[4], actB, NPOS); }
    // conv5 as FC: I=2304, O=256
    {   int NPOS = B, PG = NPOS / 16, blks = cdiv(PG * 4, 4);
        hipLaunchKernelGGL((mfconv_k<256, 36, 36, 1, 2304, 1, 1, 1, 1, 1, 4, 4>),
                           dim3(blks), dim3(256), 0, stream, actB, bfw + 565248, fold + FOLD_OFF_H[5], actA, NPOS); }
    // fc0: I=256, O=512
    {   int NPOS = B, PG = NPOS / 16, blks = cdiv(PG * 8, 4);
        hipLaunchKernelGGL((mfconv_k<512, 4, 4, 1, 256, 1, 1, 1, 1, 1, 4, 8>),
                           dim3(blks), dim3(256), 0, stream, actA, bfw + 1155072, fold + FOLD_OFF_H[6], actB, NPOS); }
    // fc1: I=512, O=512
    {   int NPOS = B, PG = NPOS / 16, blks = cdiv(PG * 8, 4);
        hipLaunchKernelGGL((mfconv_k<512, 8, 8, 1, 512, 1, 1, 1, 1, 1, 4, 8>),
                           dim3(blks), dim3(256), 0, stream, actB, bfw + 1286144, fold + FOLD_OFF_H[7], actA, NPOS); }
    // fc2 + tensor norm
    hipLaunchKernelGGL(fc_out_k, dim3(cdiv((long long)B * 10, 256)), dim3(256), 0, stream,
                       actA, tf2, scales + 8, tn_w, tn_b, tn_m, tn_v,
                       (float*)d_out, B, 512, 10);
}

// Round 5
// 422.875 us; speedup vs baseline: 45.5298x; 1.0139x over previous
//
#include <hip/hip_runtime.h>
#include <stdint.h>

#define EPSF 1e-4f

typedef int v4i __attribute__((ext_vector_type(4)));

// ---------------- workspace layout (bytes) ----------------
#define OFF_SCALES 0            // 16 floats (slots 0..5 conv, 6..8 fc)
#define OFF_FOLD   1024         // folded BN params
#define OFF_W      32768        // B-fragment weights (MFMA lane order)
#define OFF_TF2    (OFF_W + 1548288)   // fc2 ternary [10][512]
#define OFF_ACT_A  2097152
#define OFF_ACT_B  60817408

static const int FOLD_OFF_H[8] = {0,128,256,512,768,1280,1792,2816};
__device__ __constant__ int FOLD_OFF_D[8] = {0,128,256,512,768,1280,1792,2816};

// per-layer B-frag prep tables: l0..5 = conv0..5, l6=fc0, l7=fc1
__device__ __constant__ int PREP_MODE[8] = {0,1,1,1,1,1,2,2};
__device__ __constant__ int PREP_CO[8]   = {64,64,128,128,256,256,512,512};
__device__ __constant__ int PREP_CI[8]   = {3,64,64,128,128,256,256,512};
__device__ __constant__ int PREP_KC[8]   = {1,1,1,2,2,4,1,1};
__device__ __constant__ int PREP_NB[8]   = {12288,36864,73728,147456,294912,589824,131072,262144};
__device__ __constant__ int PREP_OFF[8]  = {0,12288,49152,122880,270336,565248,1155072,1286144};

// ---------------- prep kernels ----------------
__global__ void zero_scales_k(float* s) { if (threadIdx.x < 16) s[threadIdx.x] = 0.f; }

struct AbsArgs { const float* w[9]; int n[9]; };
__global__ void absmax_all_k(AbsArgs a, float* scales) {
    __shared__ float red[256];
    int l = blockIdx.x >> 4;
    int sb = blockIdx.x & 15;
    const float* w = a.w[l];
    int n = a.n[l];
    float m = 0.f;
    for (int i = sb * 256 + threadIdx.x; i < n; i += 16 * 256)
        m = fmaxf(m, fabsf(w[i]));
    red[threadIdx.x] = m;
    __syncthreads();
    for (int s2 = 128; s2 > 0; s2 >>= 1) {
        if ((int)threadIdx.x < s2) red[threadIdx.x] = fmaxf(red[threadIdx.x], red[threadIdx.x + s2]);
        __syncthreads();
    }
    if (threadIdx.x == 0) atomicMax((unsigned int*)(scales + l), __float_as_uint(red[0]));
}

__global__ void tern_fc_k(const float* __restrict__ w, int n, const float* __restrict__ slot,
                          int8_t* __restrict__ t) {
    int i = blockIdx.x * blockDim.x + threadIdx.x;
    if (i >= n) return;
    float q = fminf(fmaxf(rintf(w[i] / slot[0]), -1.f), 1.f);
    t[i] = (int8_t)q;
}

// B-fragment prep: dest byte idx = ((s*COT + ct)*64 + lane)*16 + jb
// lane = quad*16 + n ; value = W[co = ct*16+n][k = s*64 + quad*16 + jb]
struct PrepArgs { const float* w[8]; };
__global__ void bprep_all_k(PrepArgs pa, const float* __restrict__ scales,
                            int8_t* __restrict__ dst) {
    int l = blockIdx.y;
    int idx = blockIdx.x * 256 + threadIdx.x;
    if (idx >= PREP_NB[l]) return;
    const float* w = pa.w[l];
    float s = scales[l];
    int jb = idx & 15;
    int lane = (idx >> 4) & 63;
    int fct = idx >> 10;
    int quad = lane >> 4, n = lane & 15;
    int COT = PREP_CO[l] >> 4;
    int ct = fct & (COT - 1);
    int st = fct >> (31 - __clz(COT));
    int co = ct * 16 + n;
    float val;
    int md = PREP_MODE[l];
    if (md == 0) {
        // conv0, CI padded to 16: k = quad*16+jb -> dx=quad, ci=jb
        int ky = st, dx = quad, ci = jb;
        val = (dx < 3 && ci < 3) ? w[(co * 3 + ci) * 9 + ky * 3 + dx] : 0.f;
    } else if (md == 1) {
        int KC = PREP_KC[l], CI = PREP_CI[l];
        int kxy = st / KC, kc = st - kxy * KC;
        int ci = kc * 64 + quad * 16 + jb;
        val = w[(co * CI + ci) * 9 + kxy];
    } else {
        int CI = PREP_CI[l];
        int i = st * 64 + quad * 16 + jb;
        val = w[co * CI + i];
    }
    float q = fminf(fmaxf(rintf(val / s), -1.f), 1.f);
    dst[PREP_OFF[l] + idx] = (int8_t)q;
}

struct BnArgs { const float* g[8]; const float* b[8]; const float* m[8]; const float* v[8]; };
__global__ void bnfold_all_k(BnArgs ba, const float* __restrict__ scales,
                             float* __restrict__ fold) {
    int l = blockIdx.y;
    int i = blockIdx.x * 256 + threadIdx.x;
    int CO = PREP_CO[l];
    if (i >= CO) return;
    float sc = ba.g[l][i] / sqrtf(ba.v[l][i] + EPSF);
    float s_in = (l == 0) ? 0.0078125f : 1.0f;
    fold[FOLD_OFF_D[l] + i] = s_in * scales[l] * sc;
    fold[FOLD_OFF_D[l] + CO + i] = ba.b[l][i] - ba.m[l][i] * sc;
}

// input quant: NCHW float -> NHWC16 int8 (channels 3..15 zero)
__global__ void quant_in_k(const float* __restrict__ x, int4* __restrict__ o, int B) {
    int idx = blockIdx.x * blockDim.x + threadIdx.x;
    if (idx >= B * 1024) return;
    int p = idx & 1023;
    int b = idx >> 10;
    unsigned pk = 0;
#pragma unroll
    for (int c = 0; c < 3; ++c) {
        float q = rintf(x[((size_t)b * 3 + c) * 1024 + p] * 128.f);
        q = fminf(fmaxf(q, -127.f), 127.f);
        pk |= ((unsigned)((int)q & 0xff)) << (8 * c);
    }
    o[idx] = make_int4((int)pk, 0, 0, 0);
}

// ---------------- MFMA implicit-GEMM conv/FC ----------------
// A-frag: lane m=lane&15 (position), quad=lane>>4: 16B global load at
//   pos_base + (ky*IW+kx)*CI + kc*64 + quad*16   (coalesced)
// B-frag: prepped, addr = base + (s*COT+ct)*1024 + lane*16 (coalesced)
// C/D: col=lane&15 (co), row=quad*4+reg (position). Epilogue through
// wave-private LDS tile (pitch W+8 -> conflict-free byte writes).
// K-loop is explicitly software-pipelined: step s+1's A/B fragments are
// prefetched into the alternate register buffer while step s's MFMAs run.
template<int CO, int NSTEP, int KC, int KXN, int CI, int IH, int IW, int OW,
         int NPOS1, int J, int NCT, int COG>
__global__ __launch_bounds__(256, 3) void mfconv_k(
        const int8_t* __restrict__ act, const int8_t* __restrict__ bf,
        const float* __restrict__ fold, int8_t* __restrict__ out, int NPOS) {
    constexpr int W = 16 * NCT, P = W + 8, R = 16 * J;
    constexpr int COT = CO / 16;
    __shared__ int8_t lds[4][R * P];
    int lane = threadIdx.x & 63;
    int wid = threadIdx.x >> 6;
    int w = blockIdx.x * 4 + wid;
    int PG = NPOS / (16 * J);
    if (w >= PG * COG) return;
    int pg = w % PG, cg = w / PG;
    int m = lane & 15, quad = lane >> 4;
    int pos0 = pg * (16 * J);

    const int8_t* ab[J];
#pragma unroll
    for (int j = 0; j < J; ++j) {
        int pos = pos0 + j * 16 + m;
        int img = pos / NPOS1, p = pos - img * NPOS1;
        int oy = p / OW, ox = p - oy * OW;
        ab[j] = act + (size_t)((img * IH + oy) * IW + ox) * CI + quad * 16;
    }
    const int8_t* bb = bf + (size_t)(cg * NCT) * 1024 + lane * 16;

    auto ldA = [&](int s, v4i* dst) {
        int kxy = s / KC, kc = s - kxy * KC;
        int ky = kxy / KXN, kx = kxy - ky * KXN;
        int off = (ky * IW + kx) * CI + kc * 64;
#pragma unroll
        for (int j = 0; j < J; ++j) dst[j] = *(const v4i*)(ab[j] + off);
    };
    auto ldB = [&](int s, v4i* dst) {
#pragma unroll
        for (int ct = 0; ct < NCT; ++ct)
            dst[ct] = *(const v4i*)(bb + (size_t)(s * COT + ct) * 1024);
    };

    v4i Ab[2][J], Bb[2][NCT];
    v4i acc[J][NCT] = {};
    ldA(0, Ab[0]);
    ldB(0, Bb[0]);
#pragma unroll
    for (int s = 0; s < NSTEP; ++s) {
        int cb = s & 1;
        if (s + 1 < NSTEP) {
            ldA(s + 1, Ab[(s + 1) & 1]);
            ldB(s + 1, Bb[(s + 1) & 1]);
        }
#pragma unroll
        for (int j = 0; j < J; ++j)
#pragma unroll
            for (int ct = 0; ct < NCT; ++ct)
                acc[j][ct] = __builtin_amdgcn_mfma_i32_16x16x64_i8(Ab[cb][j], Bb[cb][ct], acc[j][ct], 0, 0, 0);
    }

    // epilogue: BN + 2-bit quant -> LDS byte transpose -> coalesced store
    int8_t* L = lds[wid];
#pragma unroll
    for (int ct = 0; ct < NCT; ++ct) {
        int co = (cg * NCT + ct) * 16 + m;
        float Af = fold[co], Bf = fold[CO + co];
#pragma unroll
        for (int j = 0; j < J; ++j) {
#pragma unroll
            for (int r = 0; r < 4; ++r) {
                float h = (float)acc[j][ct][r] * Af + Bf;
                int q = (int)fminf(fmaxf(rintf(h), -1.f), 1.f);
                L[(j * 16 + quad * 4 + r) * P + ct * 16 + m] = (int8_t)q;
            }
        }
    }
    constexpr int CH = (R * W / 8) / 64;
#pragma unroll
    for (int t = 0; t < CH; ++t) {
        int gid = t * 64 + lane;
        int row = gid / (W / 8), c8 = gid - row * (W / 8);
        int2 vv = *(const int2*)&L[row * P + c8 * 8];
        *(int2*)&out[(size_t)(pos0 + row) * CO + cg * W + c8 * 8] = vv;
    }
}

// ---------------- pool (int4: 16 channels per thread) ----------------
__global__ void pool_k(const int8_t* __restrict__ a, int8_t* __restrict__ o,
                       int B, int C, int IH, int IW, int OH, int OW) {
    int idx = blockIdx.x * blockDim.x + threadIdx.x;
    int c16n = C >> 4;
    int total = B * OH * OW * c16n;
    if (idx >= total) return;
    int c16 = idx % c16n;
    int t1 = idx / c16n;
    int ox = t1 % OW;
    int t2 = t1 / OW;
    int oy = t2 % OH;
    int b = t2 / OH;
    const int8_t* p = a + (((size_t)b * IH + 2 * oy) * IW + 2 * ox) * C + 16 * c16;
    int4 w0 = *(const int4*)p;
    int4 w1 = *(const int4*)(p + C);
    int4 w2 = *(const int4*)(p + (size_t)IW * C);
    int4 w3 = *(const int4*)(p + (size_t)IW * C + C);
    int4 r;
    const int* a0 = (const int*)&w0; const int* a1 = (const int*)&w1;
    const int* a2 = (const int*)&w2; const int* a3 = (const int*)&w3;
    int* rr = (int*)&r;
#pragma unroll
    for (int d = 0; d < 4; ++d) {
        unsigned v = 0;
#pragma unroll
        for (int k = 0; k < 4; ++k) {
            int x0 = (int)(int8_t)(a0[d] >> (8 * k));
            int x1 = (int)(int8_t)(a1[d] >> (8 * k));
            int x2 = (int)(int8_t)(a2[d] >> (8 * k));
            int x3 = (int)(int8_t)(a3[d] >> (8 * k));
            int mx = max(max(x0, x1), max(x2, x3));
            v |= ((unsigned)(mx & 0xff)) << (8 * k);
        }
        rr[d] = (int)v;
    }
    *(int4*)(o + (((size_t)b * OH + oy) * OW + ox) * C + 16 * c16) = r;
}

__device__ __forceinline__ int dot4(int a, int b, int c) {
#if __has_builtin(__builtin_amdgcn_sdot4)
    return __builtin_amdgcn_sdot4(a, b, c, false);
#else
    c += (int)(int8_t)(a) * (int)(int8_t)(b);
    c += (int)(int8_t)(a >> 8)  * (int)(int8_t)(b >> 8);
    c += (int)(int8_t)(a >> 16) * (int)(int8_t)(b >> 16);
    c += (int)(int8_t)(a >> 24) * (int)(int8_t)(b >> 24);
    return c;
#endif
}

// final FC + tensor norm -> float out (tiny: 1024x10x512)
__global__ void fc_out_k(const int8_t* __restrict__ a, const int8_t* __restrict__ t,
                         const float* __restrict__ slot,
                         const float* __restrict__ tw, const float* __restrict__ tb,
                         const float* __restrict__ tm, const float* __restrict__ tv,
                         float* __restrict__ out, int B, int I, int O) {
    int idx = blockIdx.x * blockDim.x + threadIdx.x;
    if (idx >= B * O) return;
    int o = idx % O;
    int b = idx / O;
    const int* ar = (const int*)(a + (size_t)b * I);
    const int* tr = (const int*)(t + (size_t)o * I);
    int acc = 0;
    for (int i = 0; i < (I >> 2); ++i) acc = dot4(ar[i], tr[i], acc);
    float sc = tw[0] / sqrtf(tv[0] + EPSF);
    out[idx] = ((float)acc * slot[0] - tm[0]) * sc + tb[0];
}

static inline unsigned cdiv(long long a, int b) { return (unsigned)((a + b - 1) / b); }

extern "C" void kernel_launch(void* const* d_in, const int* in_sizes, int n_in,
                              void* d_out, int out_size, void* d_ws, size_t ws_size,
                              hipStream_t stream) {
    const float* x = (const float*)d_in[0];
    const float* cw[6]; const float* bng[6]; const float* bnb[6];
    const float* bnm[6]; const float* bnv[6];
    for (int l = 0; l < 6; ++l) {
        cw[l]  = (const float*)d_in[1 + 5 * l + 0];
        bng[l] = (const float*)d_in[1 + 5 * l + 1];
        bnb[l] = (const float*)d_in[1 + 5 * l + 2];
        bnm[l] = (const float*)d_in[1 + 5 * l + 3];
        bnv[l] = (const float*)d_in[1 + 5 * l + 4];
    }
    const float* fw0 = (const float*)d_in[31];
    const float* fw1 = (const float*)d_in[32];
    const float* fw2 = (const float*)d_in[33];
    const float* fbn[2][4] = {
        { (const float*)d_in[34], (const float*)d_in[35], (const float*)d_in[36], (const float*)d_in[37] },
        { (const float*)d_in[38], (const float*)d_in[39], (const float*)d_in[40], (const float*)d_in[41] } };
    const float* tn_w = (const float*)d_in[42];
    const float* tn_b = (const float*)d_in[43];
    const float* tn_m = (const float*)d_in[44];
    const float* tn_v = (const float*)d_in[45];

    char* ws = (char*)d_ws;
    float* scales = (float*)(ws + OFF_SCALES);
    float* fold = (float*)(ws + OFF_FOLD);
    int8_t* bfw = (int8_t*)(ws + OFF_W);
    int8_t* tf2 = (int8_t*)(ws + OFF_TF2);
    int8_t* actA = (int8_t*)(ws + OFF_ACT_A);
    int8_t* actB = (int8_t*)(ws + OFF_ACT_B);

    const int B = in_sizes[0] / 3072;

    hipLaunchKernelGGL(zero_scales_k, dim3(1), dim3(16), 0, stream, scales);

    AbsArgs aa;
    aa.w[0]=cw[0]; aa.w[1]=cw[1]; aa.w[2]=cw[2]; aa.w[3]=cw[3]; aa.w[4]=cw[4]; aa.w[5]=cw[5];
    aa.w[6]=fw0; aa.w[7]=fw1; aa.w[8]=fw2;
    aa.n[0]=64*3*9; aa.n[1]=64*64*9; aa.n[2]=128*64*9; aa.n[3]=128*128*9;
    aa.n[4]=256*128*9; aa.n[5]=256*256*9; aa.n[6]=512*256; aa.n[7]=512*512; aa.n[8]=10*512;
    hipLaunchKernelGGL(absmax_all_k, dim3(144), dim3(256), 0, stream, aa, scales);

    hipLaunchKernelGGL(tern_fc_k, dim3(20), dim3(256), 0, stream, fw2, 5120, scales + 8, tf2);

    PrepArgs pp;
    pp.w[0]=cw[0]; pp.w[1]=cw[1]; pp.w[2]=cw[2]; pp.w[3]=cw[3]; pp.w[4]=cw[4]; pp.w[5]=cw[5];
    pp.w[6]=fw0; pp.w[7]=fw1;
    hipLaunchKernelGGL(bprep_all_k, dim3(2304, 8), dim3(256), 0, stream, pp, scales, bfw);

    BnArgs bb;
    for (int l = 0; l < 6; ++l) { bb.g[l]=bng[l]; bb.b[l]=bnb[l]; bb.m[l]=bnm[l]; bb.v[l]=bnv[l]; }
    for (int l = 0; l < 2; ++l) { bb.g[6+l]=fbn[l][0]; bb.b[6+l]=fbn[l][1]; bb.m[6+l]=fbn[l][2]; bb.v[6+l]=fbn[l][3]; }
    hipLaunchKernelGGL(bnfold_all_k, dim3(2, 8), dim3(256), 0, stream, bb, scales, fold);

    hipLaunchKernelGGL(quant_in_k, dim3(cdiv((long long)B * 1024, 256)), dim3(256), 0, stream,
                       x, (int4*)actA, B);

    // conv0: CI16(pad), 32->30, CO64, NSTEP=3 (ky), K=64 covers dx0..3 x ci
    {   int NPOS = B * 900, PG = NPOS / 64, blks = cdiv(PG * 1, 4);
        hipLaunchKernelGGL((mfconv_k<64, 3, 1, 1, 16, 32, 32, 30, 900, 4, 4, 1>),
                           dim3(blks), dim3(256), 0, stream, actA, bfw + 0, fold + FOLD_OFF_H[0], actB, NPOS); }
    // conv1: CI64, 30->28, CO64
    {   int NPOS = B * 784, PG = NPOS / 64, blks = cdiv(PG * 1, 4);
        hipLaunchKernelGGL((mfconv_k<64, 9, 1, 3, 64, 30, 30, 28, 784, 4, 4, 1>),
                           dim3(blks), dim3(256), 0, stream, actB, bfw + 12288, fold + FOLD_OFF_H[1], actA, NPOS); }
    // pool 28->14 (64ch)
    hipLaunchKernelGGL(pool_k, dim3(cdiv((long long)B * 14 * 14 * 4, 256)), dim3(256), 0, stream,
                       actA, actB, B, 64, 28, 28, 14, 14);
    // conv2: CI64, 14->12, CO128
    {   int NPOS = B * 144, PG = NPOS / 64, blks = cdiv(PG * 2, 4);
        hipLaunchKernelGGL((mfconv_k<128, 9, 1, 3, 64, 14, 14, 12, 144, 4, 4, 2>),
                           dim3(blks), dim3(256), 0, stream, actB, bfw + 49152, fold + FOLD_OFF_H[2], actA, NPOS); }
    // conv3: CI128, 12->10, CO128
    {   int NPOS = B * 100, PG = NPOS / 64, blks = cdiv(PG * 2, 4);
        hipLaunchKernelGGL((mfconv_k<128, 18, 2, 3, 128, 12, 12, 10, 100, 4, 4, 2>),
                           dim3(blks), dim3(256), 0, stream, actA, bfw + 122880, fold + FOLD_OFF_H[3], actB, NPOS); }
    // pool 10->5 (128ch)
    hipLaunchKernelGGL(pool_k, dim3(cdiv((long long)B * 5 * 5 * 8, 256)), dim3(256), 0, stream,
                       actB, actA, B, 128, 10, 10, 5, 5);
    // conv4: CI128, 5->3, CO256
    {   int NPOS = B * 9, PG = NPOS / 16, blks = cdiv(PG * 4, 4);
        hipLaunchKernelGGL((mfconv_k<256, 18, 2, 3, 128, 5, 5, 3, 9, 1, 4, 4>),
                           dim3(blks), dim3(256), 0, stream, actA, bfw + 270336, fold + FOLD_OFF_H[4], actB, NPOS); }
    // conv5 as FC: I=2304, O=256
    {   int NPOS = B, PG = NPOS / 16, blks = cdiv(PG * 4, 4);
        hipLaunchKernelGGL((mfconv_k<256, 36, 36, 1, 2304, 1, 1, 1, 1, 1, 4, 4>),
                           dim3(blks), dim3(256), 0, stream, actB, bfw + 565248, fold + FOLD_OFF_H[5], actA, NPOS); }
    // fc0: I=256, O=512
    {   int NPOS = B, PG = NPOS / 16, blks = cdiv(PG * 8, 4);
        hipLaunchKernelGGL((mfconv_k<512, 4, 4, 1, 256, 1, 1, 1, 1, 1, 4, 8>),
                           dim3(blks), dim3(256), 0, stream, actA, bfw + 1155072, fold + FOLD_OFF_H[6], actB, NPOS); }
    // fc1: I=512, O=512
    {   int NPOS = B, PG = NPOS / 16, blks = cdiv(PG * 8, 4);
        hipLaunchKernelGGL((mfconv_k<512, 8, 8, 1, 512, 1, 1, 1, 1, 1, 4, 8>),
                           dim3(blks), dim3(256), 0, stream, actB, bfw + 1286144, fold + FOLD_OFF_H[7], actA, NPOS); }
    // fc2 + tensor norm
    hipLaunchKernelGGL(fc_out_k, dim3(cdiv((long long)B * 10, 256)), dim3(256), 0, stream,
                       actA, tf2, scales + 8, tn_w, tn_b, tn_m, tn_v,
                       (float*)d_out, B, 512, 10);
}

// Round 6
// 377.164 us; speedup vs baseline: 51.0479x; 1.1212x over previous
//
#include <hip/hip_runtime.h>
#include <stdint.h>

#define EPSF 1e-4f

typedef int v4i __attribute__((ext_vector_type(4)));

// ---------------- workspace layout (bytes) ----------------
#define OFF_SCALES 0            // 16 floats (slots 0..5 conv, 6..8 fc)
#define OFF_FOLD   1024         // folded BN params
#define OFF_W      32768        // B-fragment weights (MFMA lane order)
#define OFF_TF2    (OFF_W + 1548288)   // fc2 ternary [10][512]
#define OFF_ACT_A  2097152
#define OFF_ACT_B  60817408

static const int FOLD_OFF_H[8] = {0,128,256,512,768,1280,1792,2816};
__device__ __constant__ int FOLD_OFF_D[8] = {0,128,256,512,768,1280,1792,2816};

// per-layer B-frag prep tables: l0..5 = conv0..5, l6=fc0, l7=fc1
__device__ __constant__ int PREP_MODE[8] = {0,1,1,1,1,1,2,2};
__device__ __constant__ int PREP_CO[8]   = {64,64,128,128,256,256,512,512};
__device__ __constant__ int PREP_CI[8]   = {3,64,64,128,128,256,256,512};
__device__ __constant__ int PREP_KC[8]   = {1,1,1,2,2,4,1,1};
__device__ __constant__ int PREP_NB[8]   = {12288,36864,73728,147456,294912,589824,131072,262144};
__device__ __constant__ int PREP_OFF[8]  = {0,12288,49152,122880,270336,565248,1155072,1286144};

// ---------------- prep kernels ----------------
__global__ void zero_scales_k(float* s) { if (threadIdx.x < 16) s[threadIdx.x] = 0.f; }

struct AbsArgs { const float* w[9]; int n[9]; };
__global__ void absmax_all_k(AbsArgs a, float* scales) {
    __shared__ float red[256];
    int l = blockIdx.x >> 4;
    int sb = blockIdx.x & 15;
    const float* w = a.w[l];
    int n = a.n[l];
    float m = 0.f;
    for (int i = sb * 256 + threadIdx.x; i < n; i += 16 * 256)
        m = fmaxf(m, fabsf(w[i]));
    red[threadIdx.x] = m;
    __syncthreads();
    for (int s2 = 128; s2 > 0; s2 >>= 1) {
        if ((int)threadIdx.x < s2) red[threadIdx.x] = fmaxf(red[threadIdx.x], red[threadIdx.x + s2]);
        __syncthreads();
    }
    if (threadIdx.x == 0) atomicMax((unsigned int*)(scales + l), __float_as_uint(red[0]));
}

__global__ void tern_fc_k(const float* __restrict__ w, int n, const float* __restrict__ slot,
                          int8_t* __restrict__ t) {
    int i = blockIdx.x * blockDim.x + threadIdx.x;
    if (i >= n) return;
    float q = fminf(fmaxf(rintf(w[i] / slot[0]), -1.f), 1.f);
    t[i] = (int8_t)q;
}

// B-fragment prep: dest byte idx = ((s*COT + ct)*64 + lane)*16 + jb
// lane = quad*16 + n ; value = W[co = ct*16+n][k = s*64 + quad*16 + jb]
struct PrepArgs { const float* w[8]; };
__global__ void bprep_all_k(PrepArgs pa, const float* __restrict__ scales,
                            int8_t* __restrict__ dst) {
    int l = blockIdx.y;
    int idx = blockIdx.x * 256 + threadIdx.x;
    if (idx >= PREP_NB[l]) return;
    const float* w = pa.w[l];
    float s = scales[l];
    int jb = idx & 15;
    int lane = (idx >> 4) & 63;
    int fct = idx >> 10;
    int quad = lane >> 4, n = lane & 15;
    int COT = PREP_CO[l] >> 4;
    int ct = fct & (COT - 1);
    int st = fct >> (31 - __clz(COT));
    int co = ct * 16 + n;
    float val;
    int md = PREP_MODE[l];
    if (md == 0) {
        // conv0, CI padded to 16: k = quad*16+jb -> dx=quad, ci=jb
        int ky = st, dx = quad, ci = jb;
        val = (dx < 3 && ci < 3) ? w[(co * 3 + ci) * 9 + ky * 3 + dx] : 0.f;
    } else if (md == 1) {
        int KC = PREP_KC[l], CI = PREP_CI[l];
        int kxy = st / KC, kc = st - kxy * KC;
        int ci = kc * 64 + quad * 16 + jb;
        val = w[(co * CI + ci) * 9 + kxy];
    } else {
        int CI = PREP_CI[l];
        int i = st * 64 + quad * 16 + jb;
        val = w[co * CI + i];
    }
    float q = fminf(fmaxf(rintf(val / s), -1.f), 1.f);
    dst[PREP_OFF[l] + idx] = (int8_t)q;
}

struct BnArgs { const float* g[8]; const float* b[8]; const float* m[8]; const float* v[8]; };
__global__ void bnfold_all_k(BnArgs ba, const float* __restrict__ scales,
                             float* __restrict__ fold) {
    int l = blockIdx.y;
    int i = blockIdx.x * 256 + threadIdx.x;
    int CO = PREP_CO[l];
    if (i >= CO) return;
    float sc = ba.g[l][i] / sqrtf(ba.v[l][i] + EPSF);
    float s_in = (l == 0) ? 0.0078125f : 1.0f;
    fold[FOLD_OFF_D[l] + i] = s_in * scales[l] * sc;
    fold[FOLD_OFF_D[l] + CO + i] = ba.b[l][i] - ba.m[l][i] * sc;
}

// input quant: NCHW float -> NHWC16 int8 (channels 3..15 zero)
__global__ void quant_in_k(const float* __restrict__ x, int4* __restrict__ o, int B) {
    int idx = blockIdx.x * blockDim.x + threadIdx.x;
    if (idx >= B * 1024) return;
    int p = idx & 1023;
    int b = idx >> 10;
    unsigned pk = 0;
#pragma unroll
    for (int c = 0; c < 3; ++c) {
        float q = rintf(x[((size_t)b * 3 + c) * 1024 + p] * 128.f);
        q = fminf(fmaxf(q, -127.f), 127.f);
        pk |= ((unsigned)((int)q & 0xff)) << (8 * c);
    }
    o[idx] = make_int4((int)pk, 0, 0, 0);
}

// ---------------- MFMA implicit-GEMM conv/FC ----------------
// A-frag: lane m=lane&15 (position), quad=lane>>4: 16B global load (coalesced).
// B-frag: block-uniform (all 4 waves share cg) -> staged into LDS in chunks of
//   CH steps, consumed via ds_read_b128 (lane*16: 2-way bank alias = free).
// K-loop: per step, prefetch next step's A (global) + B (ds_read) into the
//   alternate register buffer, then sched_barrier(0) pins the loads ABOVE the
//   16 MFMAs so the scheduler cannot sink them (R5 showed it otherwise does).
// C/D: col=lane&15 (co), row=quad*4+reg. Epilogue reuses the staging LDS
//   (after barrier) as wave-private byte-transpose tiles -> coalesced stores.
template<int CO, int NSTEP, int KC, int KXN, int CI, int IH, int IW, int OW,
         int NPOS1, int J, int NCT, int COG>
__global__ __launch_bounds__(256, 3) void mfconv_k(
        const int8_t* __restrict__ act, const int8_t* __restrict__ bf,
        const float* __restrict__ fold, int8_t* __restrict__ out, int NPOS) {
    constexpr int W = 16 * NCT, P = W + 8, R = 16 * J;
    constexpr int COT = CO / 16;
    constexpr int CH = NSTEP < 9 ? NSTEP : 9;     // steps per LDS chunk
    constexpr int NCHK = NSTEP / CH;              // all configs: NSTEP % CH == 0
    constexpr int STAGE_B = CH * NCT * 1024;
    constexpr int EPI_B = 4 * R * P;
    constexpr int LDS_B = STAGE_B > EPI_B ? STAGE_B : EPI_B;
    __shared__ __align__(16) int8_t lds[LDS_B];

    int lane = threadIdx.x & 63;
    int wid = threadIdx.x >> 6;
    int w = blockIdx.x * 4 + wid;                 // grid is exact: no tail waves
    int PG = NPOS / (16 * J);
    int pg = w % PG, cg = w / PG;
    int m = lane & 15, quad = lane >> 4;
    int pos0 = pg * (16 * J);

    const int8_t* ab[J];
#pragma unroll
    for (int j = 0; j < J; ++j) {
        int pos = pos0 + j * 16 + m;
        int img = pos / NPOS1, p = pos - img * NPOS1;
        int oy = p / OW, ox = p - oy * OW;
        ab[j] = act + (size_t)((img * IH + oy) * IW + ox) * CI + quad * 16;
    }

    auto ldA = [&](int s, v4i* dst) {
        int kxy = s / KC, kc = s - kxy * KC;
        int ky = kxy / KXN, kx = kxy - ky * KXN;
        int off = (ky * IW + kx) * CI + kc * 64;
#pragma unroll
        for (int j = 0; j < J; ++j) dst[j] = *(const v4i*)(ab[j] + off);
    };
    auto ldB = [&](int ls, v4i* dst) {
#pragma unroll
        for (int ct = 0; ct < NCT; ++ct)
            dst[ct] = *(const v4i*)&lds[(ls * NCT + ct) * 1024 + lane * 16];
    };

    v4i Ab[2][J], Bb[2][NCT];
    v4i acc[J][NCT] = {};

#pragma unroll
    for (int c = 0; c < NCHK; ++c) {
        int s0 = c * CH;
        __syncthreads();                          // prior chunk fully consumed
        // cooperative B staging: CH steps x NCT tiles (contiguous per step)
#pragma unroll
        for (int ls = 0; ls < CH; ++ls) {
            const int8_t* src = bf + ((size_t)((s0 + ls) * COT) + cg * NCT) * 1024;
#pragma unroll
            for (int k = 0; k < NCT / 4; ++k)
                *(v4i*)&lds[ls * NCT * 1024 + (k * 256 + (int)threadIdx.x) * 16] =
                    *(const v4i*)(src + (k * 256 + (int)threadIdx.x) * 16);
        }
        __syncthreads();
        ldA(s0, Ab[0]);
        ldB(0, Bb[0]);
#pragma unroll
        for (int ls = 0; ls < CH; ++ls) {
            int cb = ls & 1, nb = cb ^ 1;
            if (ls + 1 < CH) {
                ldA(s0 + ls + 1, Ab[nb]);
                ldB(ls + 1, Bb[nb]);
            }
            __builtin_amdgcn_sched_barrier(0);    // pin prefetch above MFMAs
#pragma unroll
            for (int j = 0; j < J; ++j)
#pragma unroll
                for (int ct = 0; ct < NCT; ++ct)
                    acc[j][ct] = __builtin_amdgcn_mfma_i32_16x16x64_i8(
                        Ab[cb][j], Bb[cb][ct], acc[j][ct], 0, 0, 0);
        }
    }

    __syncthreads();                              // staging region -> epilogue tiles
    int8_t* L = lds + wid * (R * P);
#pragma unroll
    for (int ct = 0; ct < NCT; ++ct) {
        int co = (cg * NCT + ct) * 16 + m;
        float Af = fold[co], Bf = fold[CO + co];
#pragma unroll
        for (int j = 0; j < J; ++j) {
#pragma unroll
            for (int r = 0; r < 4; ++r) {
                float h = (float)acc[j][ct][r] * Af + Bf;
                int q = (int)fminf(fmaxf(rintf(h), -1.f), 1.f);
                L[(j * 16 + quad * 4 + r) * P + ct * 16 + m] = (int8_t)q;
            }
        }
    }
    constexpr int SCH = (R * W / 8) / 64;
#pragma unroll
    for (int t = 0; t < SCH; ++t) {
        int gid = t * 64 + lane;
        int row = gid / (W / 8), c8 = gid - row * (W / 8);
        int2 vv = *(const int2*)&L[row * P + c8 * 8];
        *(int2*)&out[(size_t)(pos0 + row) * CO + cg * W + c8 * 8] = vv;
    }
}

// ---------------- pool (int4: 16 channels per thread) ----------------
__global__ void pool_k(const int8_t* __restrict__ a, int8_t* __restrict__ o,
                       int B, int C, int IH, int IW, int OH, int OW) {
    int idx = blockIdx.x * blockDim.x + threadIdx.x;
    int c16n = C >> 4;
    int total = B * OH * OW * c16n;
    if (idx >= total) return;
    int c16 = idx % c16n;
    int t1 = idx / c16n;
    int ox = t1 % OW;
    int t2 = t1 / OW;
    int oy = t2 % OH;
    int b = t2 / OH;
    const int8_t* p = a + (((size_t)b * IH + 2 * oy) * IW + 2 * ox) * C + 16 * c16;
    int4 w0 = *(const int4*)p;
    int4 w1 = *(const int4*)(p + C);
    int4 w2 = *(const int4*)(p + (size_t)IW * C);
    int4 w3 = *(const int4*)(p + (size_t)IW * C + C);
    int4 r;
    const int* a0 = (const int*)&w0; const int* a1 = (const int*)&w1;
    const int* a2 = (const int*)&w2; const int* a3 = (const int*)&w3;
    int* rr = (int*)&r;
#pragma unroll
    for (int d = 0; d < 4; ++d) {
        unsigned v = 0;
#pragma unroll
        for (int k = 0; k < 4; ++k) {
            int x0 = (int)(int8_t)(a0[d] >> (8 * k));
            int x1 = (int)(int8_t)(a1[d] >> (8 * k));
            int x2 = (int)(int8_t)(a2[d] >> (8 * k));
            int x3 = (int)(int8_t)(a3[d] >> (8 * k));
            int mx = max(max(x0, x1), max(x2, x3));
            v |= ((unsigned)(mx & 0xff)) << (8 * k);
        }
        rr[d] = (int)v;
    }
    *(int4*)(o + (((size_t)b * OH + oy) * OW + ox) * C + 16 * c16) = r;
}

__device__ __forceinline__ int dot4(int a, int b, int c) {
#if __has_builtin(__builtin_amdgcn_sdot4)
    return __builtin_amdgcn_sdot4(a, b, c, false);
#else
    c += (int)(int8_t)(a) * (int)(int8_t)(b);
    c += (int)(int8_t)(a >> 8)  * (int)(int8_t)(b >> 8);
    c += (int)(int8_t)(a >> 16) * (int)(int8_t)(b >> 16);
    c += (int)(int8_t)(a >> 24) * (int)(int8_t)(b >> 24);
    return c;
#endif
}

// final FC + tensor norm -> float out (tiny: 1024x10x512)
__global__ void fc_out_k(const int8_t* __restrict__ a, const int8_t* __restrict__ t,
                         const float* __restrict__ slot,
                         const float* __restrict__ tw, const float* __restrict__ tb,
                         const float* __restrict__ tm, const float* __restrict__ tv,
                         float* __restrict__ out, int B, int I, int O) {
    int idx = blockIdx.x * blockDim.x + threadIdx.x;
    if (idx >= B * O) return;
    int o = idx % O;
    int b = idx / O;
    const int* ar = (const int*)(a + (size_t)b * I);
    const int* tr = (const int*)(t + (size_t)o * I);
    int acc = 0;
    for (int i = 0; i < (I >> 2); ++i) acc = dot4(ar[i], tr[i], acc);
    float sc = tw[0] / sqrtf(tv[0] + EPSF);
    out[idx] = ((float)acc * slot[0] - tm[0]) * sc + tb[0];
}

static inline unsigned cdiv(long long a, int b) { return (unsigned)((a + b - 1) / b); }

extern "C" void kernel_launch(void* const* d_in, const int* in_sizes, int n_in,
                              void* d_out, int out_size, void* d_ws, size_t ws_size,
                              hipStream_t stream) {
    const float* x = (const float*)d_in[0];
    const float* cw[6]; const float* bng[6]; const float* bnb[6];
    const float* bnm[6]; const float* bnv[6];
    for (int l = 0; l < 6; ++l) {
        cw[l]  = (const float*)d_in[1 + 5 * l + 0];
        bng[l] = (const float*)d_in[1 + 5 * l + 1];
        bnb[l] = (const float*)d_in[1 + 5 * l + 2];
        bnm[l] = (const float*)d_in[1 + 5 * l + 3];
        bnv[l] = (const float*)d_in[1 + 5 * l + 4];
    }
    const float* fw0 = (const float*)d_in[31];
    const float* fw1 = (const float*)d_in[32];
    const float* fw2 = (const float*)d_in[33];
    const float* fbn[2][4] = {
        { (const float*)d_in[34], (const float*)d_in[35], (const float*)d_in[36], (const float*)d_in[37] },
        { (const float*)d_in[38], (const float*)d_in[39], (const float*)d_in[40], (const float*)d_in[41] } };
    const float* tn_w = (const float*)d_in[42];
    const float* tn_b = (const float*)d_in[43];
    const float* tn_m = (const float*)d_in[44];
    const float* tn_v = (const float*)d_in[45];

    char* ws = (char*)d_ws;
    float* scales = (float*)(ws + OFF_SCALES);
    float* fold = (float*)(ws + OFF_FOLD);
    int8_t* bfw = (int8_t*)(ws + OFF_W);
    int8_t* tf2 = (int8_t*)(ws + OFF_TF2);
    int8_t* actA = (int8_t*)(ws + OFF_ACT_A);
    int8_t* actB = (int8_t*)(ws + OFF_ACT_B);

    const int B = in_sizes[0] / 3072;

    hipLaunchKernelGGL(zero_scales_k, dim3(1), dim3(16), 0, stream, scales);

    AbsArgs aa;
    aa.w[0]=cw[0]; aa.w[1]=cw[1]; aa.w[2]=cw[2]; aa.w[3]=cw[3]; aa.w[4]=cw[4]; aa.w[5]=cw[5];
    aa.w[6]=fw0; aa.w[7]=fw1; aa.w[8]=fw2;
    aa.n[0]=64*3*9; aa.n[1]=64*64*9; aa.n[2]=128*64*9; aa.n[3]=128*128*9;
    aa.n[4]=256*128*9; aa.n[5]=256*256*9; aa.n[6]=512*256; aa.n[7]=512*512; aa.n[8]=10*512;
    hipLaunchKernelGGL(absmax_all_k, dim3(144), dim3(256), 0, stream, aa, scales);

    hipLaunchKernelGGL(tern_fc_k, dim3(20), dim3(256), 0, stream, fw2, 5120, scales + 8, tf2);

    PrepArgs pp;
    pp.w[0]=cw[0]; pp.w[1]=cw[1]; pp.w[2]=cw[2]; pp.w[3]=cw[3]; pp.w[4]=cw[4]; pp.w[5]=cw[5];
    pp.w[6]=fw0; pp.w[7]=fw1;
    hipLaunchKernelGGL(bprep_all_k, dim3(2304, 8), dim3(256), 0, stream, pp, scales, bfw);

    BnArgs bb;
    for (int l = 0; l < 6; ++l) { bb.g[l]=bng[l]; bb.b[l]=bnb[l]; bb.m[l]=bnm[l]; bb.v[l]=bnv[l]; }
    for (int l = 0; l < 2; ++l) { bb.g[6+l]=fbn[l][0]; bb.b[6+l]=fbn[l][1]; bb.m[6+l]=fbn[l][2]; bb.v[6+l]=fbn[l][3]; }
    hipLaunchKernelGGL(bnfold_all_k, dim3(2, 8), dim3(256), 0, stream, bb, scales, fold);

    hipLaunchKernelGGL(quant_in_k, dim3(cdiv((long long)B * 1024, 256)), dim3(256), 0, stream,
                       x, (int4*)actA, B);

    // conv0: CI16(pad), 32->30, CO64, NSTEP=3 (ky), K=64 covers dx0..3 x ci
    {   int NPOS = B * 900, PG = NPOS / 64, blks = (PG * 1) / 4;
        hipLaunchKernelGGL((mfconv_k<64, 3, 1, 1, 16, 32, 32, 30, 900, 4, 4, 1>),
                           dim3(blks), dim3(256), 0, stream, actA, bfw + 0, fold + FOLD_OFF_H[0], actB, NPOS); }
    // conv1: CI64, 30->28, CO64
    {   int NPOS = B * 784, PG = NPOS / 64, blks = (PG * 1) / 4;
        hipLaunchKernelGGL((mfconv_k<64, 9, 1, 3, 64, 30, 30, 28, 784, 4, 4, 1>),
                           dim3(blks), dim3(256), 0, stream, actB, bfw + 12288, fold + FOLD_OFF_H[1], actA, NPOS); }
    // pool 28->14 (64ch)
    hipLaunchKernelGGL(pool_k, dim3(cdiv((long long)B * 14 * 14 * 4, 256)), dim3(256), 0, stream,
                       actA, actB, B, 64, 28, 28, 14, 14);
    // conv2: CI64, 14->12, CO128
    {   int NPOS = B * 144, PG = NPOS / 64, blks = (PG * 2) / 4;
        hipLaunchKernelGGL((mfconv_k<128, 9, 1, 3, 64, 14, 14, 12, 144, 4, 4, 2>),
                           dim3(blks), dim3(256), 0, stream, actB, bfw + 49152, fold + FOLD_OFF_H[2], actA, NPOS); }
    // conv3: CI128, 12->10, CO128
    {   int NPOS = B * 100, PG = NPOS / 64, blks = (PG * 2) / 4;
        hipLaunchKernelGGL((mfconv_k<128, 18, 2, 3, 128, 12, 12, 10, 100, 4, 4, 2>),
                           dim3(blks), dim3(256), 0, stream, actA, bfw + 122880, fold + FOLD_OFF_H[3], actB, NPOS); }
    // pool 10->5 (128ch)
    hipLaunchKernelGGL(pool_k, dim3(cdiv((long long)B * 5 * 5 * 8, 256)), dim3(256), 0, stream,
                       actB, actA, B, 128, 10, 10, 5, 5);
    // conv4: CI128, 5->3, CO256
    {   int NPOS = B * 9, PG = NPOS / 16, blks = (PG * 4) / 4;
        hipLaunchKernelGGL((mfconv_k<256, 18, 2, 3, 128, 5, 5, 3, 9, 1, 4, 4>),
                           dim3(blks), dim3(256), 0, stream, actA, bfw + 270336, fold + FOLD_OFF_H[4], actB, NPOS); }
    // conv5 as FC: I=2304, O=256
    {   int NPOS = B, PG = NPOS / 16, blks = (PG * 4) / 4;
        hipLaunchKernelGGL((mfconv_k<256, 36, 36, 1, 2304, 1, 1, 1, 1, 1, 4, 4>),
                           dim3(blks), dim3(256), 0, stream, actB, bfw + 565248, fold + FOLD_OFF_H[5], actA, NPOS); }
    // fc0: I=256, O=512
    {   int NPOS = B, PG = NPOS / 16, blks = (PG * 8) / 4;
        hipLaunchKernelGGL((mfconv_k<512, 4, 4, 1, 256, 1, 1, 1, 1, 1, 4, 8>),
                           dim3(blks), dim3(256), 0, stream, actA, bfw + 1155072, fold + FOLD_OFF_H[6], actB, NPOS); }
    // fc1: I=512, O=512
    {   int NPOS = B, PG = NPOS / 16, blks = (PG * 8) / 4;
        hipLaunchKernelGGL((mfconv_k<512, 8, 8, 1, 512, 1, 1, 1, 1, 1, 4, 8>),
                           dim3(blks), dim3(256), 0, stream, actB, bfw + 1286144, fold + FOLD_OFF_H[7], actA, NPOS); }
    // fc2 + tensor norm
    hipLaunchKernelGGL(fc_out_k, dim3(cdiv((long long)B * 10, 256)), dim3(256), 0, stream,
                       actA, tf2, scales + 8, tn_w, tn_b, tn_m, tn_v,
                       (float*)d_out, B, 512, 10);
}

// Round 7
// 367.961 us; speedup vs baseline: 52.3247x; 1.0250x over previous
//
#include <hip/hip_runtime.h>
#include <stdint.h>

#define EPSF 1e-4f

typedef int v4i __attribute__((ext_vector_type(4)));

// ---------------- workspace layout (bytes) ----------------
#define OFF_SCALES 0            // 16 floats (slots 0..5 conv, 6..8 fc)
#define OFF_FOLD   1024         // folded BN params
#define OFF_W      32768        // B-fragment weights (MFMA lane order)
#define OFF_TF2    (OFF_W + 1548288)   // fc2 ternary [10][512]
#define OFF_ACT_A  2097152
#define OFF_ACT_B  60817408

static const int FOLD_OFF_H[8] = {0,128,256,512,768,1280,1792,2816};
__device__ __constant__ int FOLD_OFF_D[8] = {0,128,256,512,768,1280,1792,2816};

// per-layer B-frag prep tables: l0..5 = conv0..5, l6=fc0, l7=fc1
__device__ __constant__ int PREP_MODE[8] = {0,1,1,1,1,1,2,2};
__device__ __constant__ int PREP_CO[8]   = {64,64,128,128,256,256,512,512};
__device__ __constant__ int PREP_CI[8]   = {3,64,64,128,128,256,256,512};
__device__ __constant__ int PREP_KC[8]   = {1,1,1,2,2,4,1,1};
__device__ __constant__ int PREP_NB[8]   = {12288,36864,73728,147456,294912,589824,131072,262144};
__device__ __constant__ int PREP_OFF[8]  = {0,12288,49152,122880,270336,565248,1155072,1286144};

// ---------------- prep kernels ----------------
__global__ void zero_scales_k(float* s) { if (threadIdx.x < 16) s[threadIdx.x] = 0.f; }

struct AbsArgs { const float* w[9]; int n[9]; };
__global__ void absmax_all_k(AbsArgs a, float* scales) {
    __shared__ float red[256];
    int l = blockIdx.x >> 4;
    int sb = blockIdx.x & 15;
    const float* w = a.w[l];
    int n = a.n[l];
    float m = 0.f;
    for (int i = sb * 256 + threadIdx.x; i < n; i += 16 * 256)
        m = fmaxf(m, fabsf(w[i]));
    red[threadIdx.x] = m;
    __syncthreads();
    for (int s2 = 128; s2 > 0; s2 >>= 1) {
        if ((int)threadIdx.x < s2) red[threadIdx.x] = fmaxf(red[threadIdx.x], red[threadIdx.x + s2]);
        __syncthreads();
    }
    if (threadIdx.x == 0) atomicMax((unsigned int*)(scales + l), __float_as_uint(red[0]));
}

__global__ void tern_fc_k(const float* __restrict__ w, int n, const float* __restrict__ slot,
                          int8_t* __restrict__ t) {
    int i = blockIdx.x * blockDim.x + threadIdx.x;
    if (i >= n) return;
    float q = fminf(fmaxf(rintf(w[i] / slot[0]), -1.f), 1.f);
    t[i] = (int8_t)q;
}

// B-fragment prep: dest byte idx = ((s*COT + T)*64 + lane)*16 + jb
// lane = quad*16 + n ; k = s*64 + quad*16 + jb
// ct-interleaved co mapping (enables direct dword stores in the epilogue):
//   tile T = cg*4 + ct  ->  co = cg*64 + ct + 4*n
struct PrepArgs { const float* w[8]; };
__global__ void bprep_all_k(PrepArgs pa, const float* __restrict__ scales,
                            int8_t* __restrict__ dst) {
    int l = blockIdx.y;
    int idx = blockIdx.x * 256 + threadIdx.x;
    if (idx >= PREP_NB[l]) return;
    const float* w = pa.w[l];
    float s = scales[l];
    int jb = idx & 15;
    int lane = (idx >> 4) & 63;
    int fct = idx >> 10;
    int quad = lane >> 4, n = lane & 15;
    int COT = PREP_CO[l] >> 4;
    int ct = fct & (COT - 1);
    int st = fct >> (31 - __clz(COT));
    int co = (ct >> 2) * 64 + (ct & 3) + 4 * n;   // ct-interleaved
    float val;
    int md = PREP_MODE[l];
    if (md == 0) {
        // conv0, CI padded to 16: k = quad*16+jb -> dx=quad, ci=jb
        int ky = st, dx = quad, ci = jb;
        val = (dx < 3 && ci < 3) ? w[(co * 3 + ci) * 9 + ky * 3 + dx] : 0.f;
    } else if (md == 1) {
        int KC = PREP_KC[l], CI = PREP_CI[l];
        int kxy = st / KC, kc = st - kxy * KC;
        int ci = kc * 64 + quad * 16 + jb;
        val = w[(co * CI + ci) * 9 + kxy];
    } else {
        int CI = PREP_CI[l];
        int i = st * 64 + quad * 16 + jb;
        val = w[co * CI + i];
    }
    float q = fminf(fmaxf(rintf(val / s), -1.f), 1.f);
    dst[PREP_OFF[l] + idx] = (int8_t)q;
}

struct BnArgs { const float* g[8]; const float* b[8]; const float* m[8]; const float* v[8]; };
__global__ void bnfold_all_k(BnArgs ba, const float* __restrict__ scales,
                             float* __restrict__ fold) {
    int l = blockIdx.y;
    int i = blockIdx.x * 256 + threadIdx.x;
    int CO = PREP_CO[l];
    if (i >= CO) return;
    float sc = ba.g[l][i] / sqrtf(ba.v[l][i] + EPSF);
    float s_in = (l == 0) ? 0.0078125f : 1.0f;
    fold[FOLD_OFF_D[l] + i] = s_in * scales[l] * sc;
    fold[FOLD_OFF_D[l] + CO + i] = ba.b[l][i] - ba.m[l][i] * sc;
}

// input quant: NCHW float -> NHWC16 int8 (channels 3..15 zero)
__global__ void quant_in_k(const float* __restrict__ x, int4* __restrict__ o, int B) {
    int idx = blockIdx.x * blockDim.x + threadIdx.x;
    if (idx >= B * 1024) return;
    int p = idx & 1023;
    int b = idx >> 10;
    unsigned pk = 0;
#pragma unroll
    for (int c = 0; c < 3; ++c) {
        float q = rintf(x[((size_t)b * 3 + c) * 1024 + p] * 128.f);
        q = fminf(fmaxf(q, -127.f), 127.f);
        pk |= ((unsigned)((int)q & 0xff)) << (8 * c);
    }
    o[idx] = make_int4((int)pk, 0, 0, 0);
}

// ---------------- MFMA implicit-GEMM conv/FC ----------------
// A-frag: lane m=lane&15 (position), quad=lane>>4: 16B global load (coalesced).
// B-frag: block-uniform (all 4 waves share cg) -> staged into LDS in chunks of
//   CH steps, consumed via ds_read_b128 (lane*16: 2-way bank alias = free).
// K-loop: per step, prefetch next step's A (global) + B (ds_read) into the
//   alternate register buffer; sched_barrier(0) pins loads above the MFMAs.
// C/D: col=lane&15, row=quad*4+reg. With ct-interleaved B (co = cg*64+ct+4m),
//   a lane's 4 cotile bytes at fixed (j,r) are consecutive co -> pack to one
//   dword, store directly (quad's 16 lanes = one 64B segment). No LDS
//   transpose, no epilogue barrier.
template<int CO, int NSTEP, int KC, int KXN, int CI, int IH, int IW, int OW,
         int NPOS1, int J, int NCT, int COG>
__global__ __launch_bounds__(256, 3) void mfconv_k(
        const int8_t* __restrict__ act, const int8_t* __restrict__ bf,
        const float* __restrict__ fold, int8_t* __restrict__ out, int NPOS) {
    static_assert(NCT == 4, "epilogue packs 4 cotiles per dword");
    constexpr int COT = CO / 16;
    constexpr int CH = NSTEP < 9 ? NSTEP : 9;     // steps per LDS chunk
    constexpr int NCHK = NSTEP / CH;              // all configs: NSTEP % CH == 0
    __shared__ __align__(16) int8_t lds[CH * NCT * 1024];

    int lane = threadIdx.x & 63;
    int wid = threadIdx.x >> 6;
    int w = blockIdx.x * 4 + wid;                 // grid is exact: no tail waves
    int PG = NPOS / (16 * J);
    int pg = w % PG, cg = w / PG;
    int m = lane & 15, quad = lane >> 4;
    int pos0 = pg * (16 * J);

    const int8_t* ab[J];
#pragma unroll
    for (int j = 0; j < J; ++j) {
        int pos = pos0 + j * 16 + m;
        int img = pos / NPOS1, p = pos - img * NPOS1;
        int oy = p / OW, ox = p - oy * OW;
        ab[j] = act + (size_t)((img * IH + oy) * IW + ox) * CI + quad * 16;
    }

    auto ldA = [&](int s, v4i* dst) {
        int kxy = s / KC, kc = s - kxy * KC;
        int ky = kxy / KXN, kx = kxy - ky * KXN;
        int off = (ky * IW + kx) * CI + kc * 64;
#pragma unroll
        for (int j = 0; j < J; ++j) dst[j] = *(const v4i*)(ab[j] + off);
    };
    auto ldB = [&](int ls, v4i* dst) {
#pragma unroll
        for (int ct = 0; ct < NCT; ++ct)
            dst[ct] = *(const v4i*)&lds[(ls * NCT + ct) * 1024 + lane * 16];
    };

    v4i Ab[2][J], Bb[2][NCT];
    v4i acc[J][NCT] = {};

#pragma unroll
    for (int c = 0; c < NCHK; ++c) {
        int s0 = c * CH;
        __syncthreads();                          // prior chunk fully consumed
        // cooperative B staging: CH steps x NCT tiles (contiguous per step)
#pragma unroll
        for (int ls = 0; ls < CH; ++ls) {
            const int8_t* src = bf + ((size_t)((s0 + ls) * COT) + cg * NCT) * 1024;
#pragma unroll
            for (int k = 0; k < NCT / 4; ++k)
                *(v4i*)&lds[ls * NCT * 1024 + (k * 256 + (int)threadIdx.x) * 16] =
                    *(const v4i*)(src + (k * 256 + (int)threadIdx.x) * 16);
        }
        __syncthreads();
        ldA(s0, Ab[0]);
        ldB(0, Bb[0]);
#pragma unroll
        for (int ls = 0; ls < CH; ++ls) {
            int cb = ls & 1, nb = cb ^ 1;
            if (ls + 1 < CH) {
                ldA(s0 + ls + 1, Ab[nb]);
                ldB(ls + 1, Bb[nb]);
            }
            __builtin_amdgcn_sched_barrier(0);    // pin prefetch above MFMAs
#pragma unroll
            for (int j = 0; j < J; ++j)
#pragma unroll
                for (int ct = 0; ct < NCT; ++ct)
                    acc[j][ct] = __builtin_amdgcn_mfma_i32_16x16x64_i8(
                        Ab[cb][j], Bb[cb][ct], acc[j][ct], 0, 0, 0);
        }
    }

    // epilogue: BN + 2-bit quant, pack 4 consecutive co bytes -> direct stores
    float Af[NCT], Bf[NCT];
#pragma unroll
    for (int ct = 0; ct < NCT; ++ct) {
        int co = cg * 64 + ct + 4 * m;
        Af[ct] = fold[co];
        Bf[ct] = fold[CO + co];
    }
#pragma unroll
    for (int j = 0; j < J; ++j) {
#pragma unroll
        for (int r = 0; r < 4; ++r) {
            unsigned pk = 0;
#pragma unroll
            for (int ct = 0; ct < NCT; ++ct) {
                float h = (float)acc[j][ct][r] * Af[ct] + Bf[ct];
                int q = (int)fminf(fmaxf(rintf(h), -1.f), 1.f);
                pk |= ((unsigned)(q & 0xff)) << (8 * ct);
            }
            *(int*)&out[(size_t)(pos0 + j * 16 + quad * 4 + r) * CO + cg * 64 + 4 * m] = (int)pk;
        }
    }
}

// ---------------- pool (int4: 16 channels per thread) ----------------
__global__ void pool_k(const int8_t* __restrict__ a, int8_t* __restrict__ o,
                       int B, int C, int IH, int IW, int OH, int OW) {
    int idx = blockIdx.x * blockDim.x + threadIdx.x;
    int c16n = C >> 4;
    int total = B * OH * OW * c16n;
    if (idx >= total) return;
    int c16 = idx % c16n;
    int t1 = idx / c16n;
    int ox = t1 % OW;
    int t2 = t1 / OW;
    int oy = t2 % OH;
    int b = t2 / OH;
    const int8_t* p = a + (((size_t)b * IH + 2 * oy) * IW + 2 * ox) * C + 16 * c16;
    int4 w0 = *(const int4*)p;
    int4 w1 = *(const int4*)(p + C);
    int4 w2 = *(const int4*)(p + (size_t)IW * C);
    int4 w3 = *(const int4*)(p + (size_t)IW * C + C);
    int4 r;
    const int* a0 = (const int*)&w0; const int* a1 = (const int*)&w1;
    const int* a2 = (const int*)&w2; const int* a3 = (const int*)&w3;
    int* rr = (int*)&r;
#pragma unroll
    for (int d = 0; d < 4; ++d) {
        unsigned v = 0;
#pragma unroll
        for (int k = 0; k < 4; ++k) {
            int x0 = (int)(int8_t)(a0[d] >> (8 * k));
            int x1 = (int)(int8_t)(a1[d] >> (8 * k));
            int x2 = (int)(int8_t)(a2[d] >> (8 * k));
            int x3 = (int)(int8_t)(a3[d] >> (8 * k));
            int mx = max(max(x0, x1), max(x2, x3));
            v |= ((unsigned)(mx & 0xff)) << (8 * k);
        }
        rr[d] = (int)v;
    }
    *(int4*)(o + (((size_t)b * OH + oy) * OW + ox) * C + 16 * c16) = r;
}

__device__ __forceinline__ int dot4(int a, int b, int c) {
#if __has_builtin(__builtin_amdgcn_sdot4)
    return __builtin_amdgcn_sdot4(a, b, c, false);
#else
    c += (int)(int8_t)(a) * (int)(int8_t)(b);
    c += (int)(int8_t)(a >> 8)  * (int)(int8_t)(b >> 8);
    c += (int)(int8_t)(a >> 16) * (int)(int8_t)(b >> 16);
    c += (int)(int8_t)(a >> 24) * (int)(int8_t)(b >> 24);
    return c;
#endif
}

// final FC + tensor norm -> float out (tiny: 1024x10x512)
__global__ void fc_out_k(const int8_t* __restrict__ a, const int8_t* __restrict__ t,
                         const float* __restrict__ slot,
                         const float* __restrict__ tw, const float* __restrict__ tb,
                         const float* __restrict__ tm, const float* __restrict__ tv,
                         float* __restrict__ out, int B, int I, int O) {
    int idx = blockIdx.x * blockDim.x + threadIdx.x;
    if (idx >= B * O) return;
    int o = idx % O;
    int b = idx / O;
    const int* ar = (const int*)(a + (size_t)b * I);
    const int* tr = (const int*)(t + (size_t)o * I);
    int acc = 0;
    for (int i = 0; i < (I >> 2); ++i) acc = dot4(ar[i], tr[i], acc);
    float sc = tw[0] / sqrtf(tv[0] + EPSF);
    out[idx] = ((float)acc * slot[0] - tm[0]) * sc + tb[0];
}

static inline unsigned cdiv(long long a, int b) { return (unsigned)((a + b - 1) / b); }

extern "C" void kernel_launch(void* const* d_in, const int* in_sizes, int n_in,
                              void* d_out, int out_size, void* d_ws, size_t ws_size,
                              hipStream_t stream) {
    const float* x = (const float*)d_in[0];
    const float* cw[6]; const float* bng[6]; const float* bnb[6];
    const float* bnm[6]; const float* bnv[6];
    for (int l = 0; l < 6; ++l) {
        cw[l]  = (const float*)d_in[1 + 5 * l + 0];
        bng[l] = (const float*)d_in[1 + 5 * l + 1];
        bnb[l] = (const float*)d_in[1 + 5 * l + 2];
        bnm[l] = (const float*)d_in[1 + 5 * l + 3];
        bnv[l] = (const float*)d_in[1 + 5 * l + 4];
    }
    const float* fw0 = (const float*)d_in[31];
    const float* fw1 = (const float*)d_in[32];
    const float* fw2 = (const float*)d_in[33];
    const float* fbn[2][4] = {
        { (const float*)d_in[34], (const float*)d_in[35], (const float*)d_in[36], (const float*)d_in[37] },
        { (const float*)d_in[38], (const float*)d_in[39], (const float*)d_in[40], (const float*)d_in[41] } };
    const float* tn_w = (const float*)d_in[42];
    const float* tn_b = (const float*)d_in[43];
    const float* tn_m = (const float*)d_in[44];
    const float* tn_v = (const float*)d_in[45];

    char* ws = (char*)d_ws;
    float* scales = (float*)(ws + OFF_SCALES);
    float* fold = (float*)(ws + OFF_FOLD);
    int8_t* bfw = (int8_t*)(ws + OFF_W);
    int8_t* tf2 = (int8_t*)(ws + OFF_TF2);
    int8_t* actA = (int8_t*)(ws + OFF_ACT_A);
    int8_t* actB = (int8_t*)(ws + OFF_ACT_B);

    const int B = in_sizes[0] / 3072;

    hipLaunchKernelGGL(zero_scales_k, dim3(1), dim3(16), 0, stream, scales);

    AbsArgs aa;
    aa.w[0]=cw[0]; aa.w[1]=cw[1]; aa.w[2]=cw[2]; aa.w[3]=cw[3]; aa.w[4]=cw[4]; aa.w[5]=cw[5];
    aa.w[6]=fw0; aa.w[7]=fw1; aa.w[8]=fw2;
    aa.n[0]=64*3*9; aa.n[1]=64*64*9; aa.n[2]=128*64*9; aa.n[3]=128*128*9;
    aa.n[4]=256*128*9; aa.n[5]=256*256*9; aa.n[6]=512*256; aa.n[7]=512*512; aa.n[8]=10*512;
    hipLaunchKernelGGL(absmax_all_k, dim3(144), dim3(256), 0, stream, aa, scales);

    hipLaunchKernelGGL(tern_fc_k, dim3(20), dim3(256), 0, stream, fw2, 5120, scales + 8, tf2);

    PrepArgs pp;
    pp.w[0]=cw[0]; pp.w[1]=cw[1]; pp.w[2]=cw[2]; pp.w[3]=cw[3]; pp.w[4]=cw[4]; pp.w[5]=cw[5];
    pp.w[6]=fw0; pp.w[7]=fw1;
    hipLaunchKernelGGL(bprep_all_k, dim3(2304, 8), dim3(256), 0, stream, pp, scales, bfw);

    BnArgs bb;
    for (int l = 0; l < 6; ++l) { bb.g[l]=bng[l]; bb.b[l]=bnb[l]; bb.m[l]=bnm[l]; bb.v[l]=bnv[l]; }
    for (int l = 0; l < 2; ++l) { bb.g[6+l]=fbn[l][0]; bb.b[6+l]=fbn[l][1]; bb.m[6+l]=fbn[l][2]; bb.v[6+l]=fbn[l][3]; }
    hipLaunchKernelGGL(bnfold_all_k, dim3(2, 8), dim3(256), 0, stream, bb, scales, fold);

    hipLaunchKernelGGL(quant_in_k, dim3(cdiv((long long)B * 1024, 256)), dim3(256), 0, stream,
                       x, (int4*)actA, B);

    // conv0: CI16(pad), 32->30, CO64, NSTEP=3 (ky), K=64 covers dx0..3 x ci
    {   int NPOS = B * 900, PG = NPOS / 64, blks = (PG * 1) / 4;
        hipLaunchKernelGGL((mfconv_k<64, 3, 1, 1, 16, 32, 32, 30, 900, 4, 4, 1>),
                           dim3(blks), dim3(256), 0, stream, actA, bfw + 0, fold + FOLD_OFF_H[0], actB, NPOS); }
    // conv1: CI64, 30->28, CO64
    {   int NPOS = B * 784, PG = NPOS / 64, blks = (PG * 1) / 4;
        hipLaunchKernelGGL((mfconv_k<64, 9, 1, 3, 64, 30, 30, 28, 784, 4, 4, 1>),
                           dim3(blks), dim3(256), 0, stream, actB, bfw + 12288, fold + FOLD_OFF_H[1], actA, NPOS); }
    // pool 28->14 (64ch)
    hipLaunchKernelGGL(pool_k, dim3(cdiv((long long)B * 14 * 14 * 4, 256)), dim3(256), 0, stream,
                       actA, actB, B, 64, 28, 28, 14, 14);
    // conv2: CI64, 14->12, CO128
    {   int NPOS = B * 144, PG = NPOS / 64, blks = (PG * 2) / 4;
        hipLaunchKernelGGL((mfconv_k<128, 9, 1, 3, 64, 14, 14, 12, 144, 4, 4, 2>),
                           dim3(blks), dim3(256), 0, stream, actB, bfw + 49152, fold + FOLD_OFF_H[2], actA, NPOS); }
    // conv3: CI128, 12->10, CO128
    {   int NPOS = B * 100, PG = NPOS / 64, blks = (PG * 2) / 4;
        hipLaunchKernelGGL((mfconv_k<128, 18, 2, 3, 128, 12, 12, 10, 100, 4, 4, 2>),
                           dim3(blks), dim3(256), 0, stream, actA, bfw + 122880, fold + FOLD_OFF_H[3], actB, NPOS); }
    // pool 10->5 (128ch)
    hipLaunchKernelGGL(pool_k, dim3(cdiv((long long)B * 5 * 5 * 8, 256)), dim3(256), 0, stream,
                       actB, actA, B, 128, 10, 10, 5, 5);
    // conv4: CI128, 5->3, CO256
    {   int NPOS = B * 9, PG = NPOS / 16, blks = (PG * 4) / 4;
        hipLaunchKernelGGL((mfconv_k<256, 18, 2, 3, 128, 5, 5, 3, 9, 1, 4, 4>),
                           dim3(blks), dim3(256), 0, stream, actA, bfw + 270336, fold + FOLD_OFF_H[4], actB, NPOS); }
    // conv5 as FC: I=2304, O=256
    {   int NPOS = B, PG = NPOS / 16, blks = (PG * 4) / 4;
        hipLaunchKernelGGL((mfconv_k<256, 36, 36, 1, 2304, 1, 1, 1, 1, 1, 4, 4>),
                           dim3(blks), dim3(256), 0, stream, actB, bfw + 565248, fold + FOLD_OFF_H[5], actA, NPOS); }
    // fc0: I=256, O=512
    {   int NPOS = B, PG = NPOS / 16, blks = (PG * 8) / 4;
        hipLaunchKernelGGL((mfconv_k<512, 4, 4, 1, 256, 1, 1, 1, 1, 1, 4, 8>),
                           dim3(blks), dim3(256), 0, stream, actA, bfw + 1155072, fold + FOLD_OFF_H[6], actB, NPOS); }
    // fc1: I=512, O=512
    {   int NPOS = B, PG = NPOS / 16, blks = (PG * 8) / 4;
        hipLaunchKernelGGL((mfconv_k<512, 8, 8, 1, 512, 1, 1, 1, 1, 1, 4, 8>),
                           dim3(blks), dim3(256), 0, stream, actB, bfw + 1286144, fold + FOLD_OFF_H[7], actA, NPOS); }
    // fc2 + tensor norm
    hipLaunchKernelGGL(fc_out_k, dim3(cdiv((long long)B * 10, 256)), dim3(256), 0, stream,
                       actA, tf2, scales + 8, tn_w, tn_b, tn_m, tn_v,
                       (float*)d_out, B, 512, 10);
}